// Round 6
// baseline (359.200 us; speedup 1.0000x reference)
//
#include <hip/hip_runtime.h>
#include <hip/hip_bf16.h>

#define THREADS 256

typedef __attribute__((ext_vector_type(8))) short bfrag;     // 8 bf16 = 4 VGPR
typedef __attribute__((ext_vector_type(4))) float f32x4;     // MFMA accumulator

__device__ inline unsigned short f2b(float v) {
    __hip_bfloat16 b = __float2bfloat16(v);
    return *reinterpret_cast<unsigned short*>(&b);
}
__device__ inline float b2f(unsigned short u) {
    return __uint_as_float(((unsigned)u) << 16);
}
__device__ inline float rdv(const void* p, int off, bool isbf) {
    return isbf ? b2f(((const unsigned short*)p)[off]) : ((const float*)p)[off];
}

// ---------------- dtype detection (bf16 vs fp32 inputs) ----------------
__global__ void detect_kernel(const unsigned short* __restrict__ x, int n, int* flag) {
    __shared__ int cnt;
    if (threadIdx.x == 0) cnt = 0;
    __syncthreads();
    int local = 0;
    for (int i = threadIdx.x; i < n; i += THREADS) {
        unsigned ex = (x[i] >> 7) & 0xFF;
        if (ex == 0xFF || ex >= 134 || (ex > 0 && ex <= 100)) local++;
    }
    atomicAdd(&cnt, local);
    __syncthreads();
    if (threadIdx.x == 0) *flag = (cnt * 8 > n) ? 0 : 1;  // 1 = bf16
}

// ---------------- fused prep: W->frag-order, BN fold, degree count, xconv ----------------
struct InPtrs { const void* p[23]; };

__global__ void prep_kernel(InPtrs in, const int* __restrict__ flag,
                            unsigned short* __restrict__ Wl1, unsigned short* __restrict__ Wl2,
                            unsigned short* __restrict__ WlR, unsigned short* __restrict__ Wl3,
                            float* __restrict__ bnsc1, float* __restrict__ bnsh1,
                            float* __restrict__ bnsc2, float* __restrict__ bnsh2,
                            float* __restrict__ AS1f, float* __restrict__ AD1f,
                            float* __restrict__ AS2f, float* __restrict__ AD2f,
                            float* __restrict__ AS3f, float* __restrict__ AD3f,
                            float* __restrict__ B3f, unsigned short* __restrict__ xb,
                            int N, const int* __restrict__ ei, int* __restrict__ deg,
                            int E, int CB) {
    bool isbf = (*flag != 0);
    int b = blockIdx.x;
    if (b < 27) {
        // W [128,cols] raw -> bf16 fragment order
        const void* Wv; unsigned short* o; int cols, tt;
        if (b < 8)       { Wv = in.p[2];  o = Wl1; cols = 128; tt = b; }
        else if (b < 16) { Wv = in.p[6];  o = Wl2; cols = 128; tt = b - 8; }
        else if (b < 24) { Wv = in.p[14]; o = WlR; cols = 128; tt = b - 16; }
        else             { Wv = in.p[10]; o = Wl3; cols = 40;  tt = b - 24; }
        int id = tt * 256 + threadIdx.x;
        int t = id >> 8, ks = (id >> 6) & 3, l = id & 63;
        int q = l >> 4, n = l & 15;
        int c = t * 16 + n;
#pragma unroll
        for (int j = 0; j < 8; ++j) {
            int k = ks * 32 + q * 8 + j;
            float v = (c < cols) ? rdv(Wv, k * cols + c, isbf) : 0.f;
            o[id * 8 + j] = f2b(v);
        }
    } else if (b == 27) {
        int c = threadIdx.x;
        if (c < 128) {
            float s = rdv(in.p[15], c, isbf) * rsqrtf(rdv(in.p[18], c, isbf) + 1e-5f);
            bnsc1[c] = s;
            bnsh1[c] = rdv(in.p[16], c, isbf) - rdv(in.p[17], c, isbf) * s +
                       rdv(in.p[5], c, isbf) * s;
            AS1f[c] = rdv(in.p[3], c, isbf);
            AD1f[c] = rdv(in.p[4], c, isbf);
            AS2f[c] = rdv(in.p[7], c, isbf);
            AD2f[c] = rdv(in.p[8], c, isbf);
        } else {
            int d = c - 128;
            float s = rdv(in.p[19], d, isbf) * rsqrtf(rdv(in.p[22], d, isbf) + 1e-5f);
            bnsc2[d] = s;
            bnsh2[d] = rdv(in.p[20], d, isbf) - rdv(in.p[21], d, isbf) * s +
                       rdv(in.p[9], d, isbf) * s;
            if (d < 40) {
                AS3f[d] = rdv(in.p[11], d, isbf);
                AD3f[d] = rdv(in.p[12], d, isbf);
                B3f[d] = rdv(in.p[13], d, isbf);
            }
        }
    } else if (b < 28 + CB) {
        int i = (b - 28) * 256 + threadIdx.x;
        if (i < E + N) {
            int d = (i < E) ? ei[E + i] : (i - E);
            atomicAdd(&deg[d], 1);
        }
    } else {
        if (isbf) return;  // bf16 path: gemm reads d_in[0] raw
        const float* xf = (const float*)in.p[0];
        int total = N * 128;
        int stride = (gridDim.x - 28 - CB) * 256;
        for (int i = (b - 28 - CB) * 256 + threadIdx.x; i < total; i += stride)
            xb[i] = f2b(xf[i]);
    }
}

// ---------------- CSR scan stages ----------------
__global__ void bsum_kernel(const int* __restrict__ deg, int* __restrict__ bsum, int N) {
    int idx = blockIdx.x * 256 + threadIdx.x;
    int lane = threadIdx.x & 63, wv = threadIdx.x >> 6;
    int v = (idx < N) ? deg[idx] : 0;
#pragma unroll
    for (int o = 1; o < 64; o <<= 1) v += __shfl_xor(v, o, 64);
    __shared__ int ws[4];
    if (lane == 0) ws[wv] = v;
    __syncthreads();
    if (threadIdx.x == 0) bsum[blockIdx.x] = ws[0] + ws[1] + ws[2] + ws[3];
}

__global__ __launch_bounds__(1024) void bscan_kernel(const int* __restrict__ bsum,
                                                     int* __restrict__ boff, int nb) {
    __shared__ int ws[16];
    int tid = threadIdx.x, lane = tid & 63, wv = tid >> 6;
    int v = (tid < nb) ? bsum[tid] : 0;
    int sc = v;
#pragma unroll
    for (int o = 1; o < 64; o <<= 1) {
        int t = __shfl_up(sc, o, 64);
        if (lane >= o) sc += t;
    }
    if (lane == 63) ws[wv] = sc;
    __syncthreads();
    int add = 0;
#pragma unroll
    for (int k = 0; k < 16; ++k) add += (k < wv) ? ws[k] : 0;
    if (tid < nb) boff[tid] = add + sc - v;
}

__global__ void scanw_kernel(const int* __restrict__ deg, const int* __restrict__ boff,
                             int* __restrict__ row_ptr, int* __restrict__ pos, int N) {
    int idx = blockIdx.x * 256 + threadIdx.x;
    int lane = threadIdx.x & 63, wv = threadIdx.x >> 6;
    int v = (idx < N) ? deg[idx] : 0;
    int sc = v;
#pragma unroll
    for (int o = 1; o < 64; o <<= 1) {
        int t = __shfl_up(sc, o, 64);
        if (lane >= o) sc += t;
    }
    __shared__ int ws[4];
    if (lane == 63) ws[wv] = sc;
    __syncthreads();
    int add = boff[blockIdx.x];
#pragma unroll
    for (int k = 0; k < 4; ++k) add += (k < wv) ? ws[k] : 0;
    int excl = add + sc - v;
    if (idx < N) {
        pos[idx] = excl;
        row_ptr[idx + 1] = excl + v;
    }
    if (idx == 0) row_ptr[0] = 0;
}

__global__ void scatter_kernel(const int* __restrict__ ei, int* __restrict__ pos,
                               int* __restrict__ csr, int E, int N) {
    int e = blockIdx.x * THREADS + threadIdx.x;
    if (e >= E + N) return;
    int s, d;
    if (e < E) { s = ei[e]; d = ei[E + e]; }
    else { s = e - E; d = s; }
    int p = atomicAdd(&pos[d], 1);
    csr[p] = s;
}

// ---------------- MFMA GEMM: [N,128]bf16 @ [128,cols]bf16 ----------------
// A addressing: frag = A + ar*aRow + ks*aKs + q*8 (row-major: aRow=128,aKs=32;
// head-blocked [4][N][32]: aRow=32, aKs=N*32).
// C: CBLK -> head-blocked [col>>5][N][32]; else row-major ldc.
// es/ed stored transposed [H][N].
template <int COLT, int HEADS, bool ES, bool CBLK>
__global__ __launch_bounds__(256) void gemm_mfma(
    const unsigned short* __restrict__ A, const unsigned short* __restrict__ Wg,
    const float* __restrict__ as_f, const float* __restrict__ ad_f,
    unsigned short* __restrict__ out, int ldc, int cols,
    float* __restrict__ es, float* __restrict__ ed, int N,
    long aRow, long aKs) {
    __shared__ __align__(16) unsigned short Wls[COLT * 2048];
    int tid = threadIdx.x;
    {
        const float4* src = (const float4*)Wg;
        float4* dst = (float4*)Wls;
#pragma unroll
        for (int i = 0; i < COLT; ++i) dst[tid + i * 256] = src[tid + i * 256];
    }
    __syncthreads();
    int w = tid >> 6, lane = tid & 63;
    int n = lane & 15, q = lane >> 4;
    int row0 = blockIdx.x * 64 + w * 16;
    int ar = row0 + n; ar = ar < N ? ar : N - 1;   // clamp: OOB rows harmless
    f32x4 acc[COLT];
#pragma unroll
    for (int t = 0; t < COLT; ++t) acc[t] = (f32x4){0.f, 0.f, 0.f, 0.f};
    const unsigned short* abase = A + (size_t)ar * aRow;
#pragma unroll
    for (int ks = 0; ks < 4; ++ks) {
        bfrag a = *reinterpret_cast<const bfrag*>(abase + (size_t)ks * aKs + q * 8);
#pragma unroll
        for (int t = 0; t < COLT; ++t) {
            bfrag b = *reinterpret_cast<const bfrag*>(&Wls[((t * 4 + ks) * 64 + lane) * 8]);
            acc[t] = __builtin_amdgcn_mfma_f32_16x16x32_bf16(a, b, acc[t], 0, 0, 0);
        }
    }
    if (ES) {
        float asv[COLT], adv[COLT];
#pragma unroll
        for (int t = 0; t < COLT; ++t) {
            int c = t * 16 + n;
            asv[t] = (c < cols) ? as_f[c] : 0.f;
            adv[t] = (c < cols) ? ad_f[c] : 0.f;
        }
#pragma unroll
        for (int r = 0; r < 4; ++r) {
            float pe[HEADS], pd[HEADS];
#pragma unroll
            for (int h = 0; h < HEADS; ++h) { pe[h] = 0.f; pd[h] = 0.f; }
#pragma unroll
            for (int t = 0; t < COLT; ++t) {
                int h = (HEADS == 4) ? (t >> 1) : 0;
                pe[h] = fmaf(acc[t][r], asv[t], pe[h]);
                pd[h] = fmaf(acc[t][r], adv[t], pd[h]);
            }
#pragma unroll
            for (int h = 0; h < HEADS; ++h) {
#pragma unroll
                for (int o = 1; o < 16; o <<= 1) {
                    pe[h] += __shfl_xor(pe[h], o, 64);
                    pd[h] += __shfl_xor(pd[h], o, 64);
                }
            }
            int row = row0 + q * 4 + r;
            if (n == 0 && row < N) {
#pragma unroll
                for (int h = 0; h < HEADS; ++h) {
                    es[(size_t)h * N + row] = pe[h];
                    ed[(size_t)h * N + row] = pd[h];
                }
            }
        }
    }
#pragma unroll
    for (int t = 0; t < COLT; ++t) {
        int col = t * 16 + n;
        if (col < cols) {
#pragma unroll
            for (int r = 0; r < 4; ++r) {
                int row = row0 + q * 4 + r;
                if (row < N) {
                    if (CBLK)
                        out[(size_t)(col >> 5) * N * 32 + (size_t)row * 32 + (col & 31)] =
                            f2b(acc[t][r]);
                    else
                        out[(size_t)row * ldc + col] = f2b(acc[t][r]);
                }
            }
        }
    }
}

// W1 + Wres in one pass (A read once); C outputs head-blocked bf16
__global__ __launch_bounds__(256) void gemm_dual(
    const unsigned short* __restrict__ Araw, const unsigned short* __restrict__ Acvt,
    const int* __restrict__ flag,
    const unsigned short* __restrict__ Wg1, const unsigned short* __restrict__ WgR,
    const float* __restrict__ as_f, const float* __restrict__ ad_f,
    unsigned short* __restrict__ xwb, unsigned short* __restrict__ resb,
    float* __restrict__ es, float* __restrict__ ed, int N) {
    __shared__ __align__(16) unsigned short Wls[16 * 2048];
    int tid = threadIdx.x;
    {
        const float4* s1 = (const float4*)Wg1;
        const float4* s2 = (const float4*)WgR;
        float4* dst = (float4*)Wls;
#pragma unroll
        for (int i = 0; i < 8; ++i) dst[tid + i * 256] = s1[tid + i * 256];
#pragma unroll
        for (int i = 0; i < 8; ++i) dst[2048 + tid + i * 256] = s2[tid + i * 256];
    }
    const unsigned short* A = (*flag) ? Araw : Acvt;
    __syncthreads();
    int w = tid >> 6, lane = tid & 63;
    int n = lane & 15, q = lane >> 4;
    int row0 = blockIdx.x * 64 + w * 16;
    int ar = row0 + n; ar = ar < N ? ar : N - 1;
    f32x4 acc[16];
#pragma unroll
    for (int t = 0; t < 16; ++t) acc[t] = (f32x4){0.f, 0.f, 0.f, 0.f};
    const unsigned short* arow = A + (size_t)ar * 128;
#pragma unroll
    for (int ks = 0; ks < 4; ++ks) {
        bfrag a = *reinterpret_cast<const bfrag*>(arow + ks * 32 + q * 8);
#pragma unroll
        for (int t = 0; t < 8; ++t) {
            bfrag b = *reinterpret_cast<const bfrag*>(&Wls[((t * 4 + ks) * 64 + lane) * 8]);
            acc[t] = __builtin_amdgcn_mfma_f32_16x16x32_bf16(a, b, acc[t], 0, 0, 0);
        }
#pragma unroll
        for (int t = 0; t < 8; ++t) {
            bfrag b = *reinterpret_cast<const bfrag*>(&Wls[16384 + ((t * 4 + ks) * 64 + lane) * 8]);
            acc[8 + t] = __builtin_amdgcn_mfma_f32_16x16x32_bf16(a, b, acc[8 + t], 0, 0, 0);
        }
    }
    float asv[8], adv[8];
#pragma unroll
    for (int t = 0; t < 8; ++t) {
        int c = t * 16 + n;
        asv[t] = as_f[c];
        adv[t] = ad_f[c];
    }
#pragma unroll
    for (int r = 0; r < 4; ++r) {
        float pe[4] = {0.f, 0.f, 0.f, 0.f}, pd[4] = {0.f, 0.f, 0.f, 0.f};
#pragma unroll
        for (int t = 0; t < 8; ++t) {
            int h = t >> 1;
            pe[h] = fmaf(acc[t][r], asv[t], pe[h]);
            pd[h] = fmaf(acc[t][r], adv[t], pd[h]);
        }
#pragma unroll
        for (int h = 0; h < 4; ++h) {
#pragma unroll
            for (int o = 1; o < 16; o <<= 1) {
                pe[h] += __shfl_xor(pe[h], o, 64);
                pd[h] += __shfl_xor(pd[h], o, 64);
            }
        }
        int row = row0 + q * 4 + r;
        if (n == 0 && row < N) {
#pragma unroll
            for (int h = 0; h < 4; ++h) {
                es[(size_t)h * N + row] = pe[h];
                ed[(size_t)h * N + row] = pd[h];
            }
        }
    }
#pragma unroll
    for (int t = 0; t < 8; ++t) {
        int col = t * 16 + n;
#pragma unroll
        for (int r = 0; r < 4; ++r) {
            int row = row0 + q * 4 + r;
            if (row < N) {
                size_t o = (size_t)(col >> 5) * N * 32 + (size_t)row * 32 + (col & 31);
                xwb[o] = f2b(acc[t][r]);
                resb[o] = f2b(acc[8 + t][r]);
            }
        }
    }
}

// ---------------- agg layers 1-2, head-blocked multi-pass + fused BN/res/ELU ----------------
// 4 passes (pass = head). Per pass the gather slice xwb[pass] is 3.2 MB -> per-XCD
// L2 resident. Wave = 4 nodes x 16 lanes (2ch each); exact-degree loops; den
// computed redundantly per lane (no cross-lane ops); csr prefetched 1 ahead.
__global__ __launch_bounds__(256) void agg128_mp(
    const unsigned short* __restrict__ xwb, const float* __restrict__ es,
    const float* __restrict__ ed, const int* __restrict__ row_ptr,
    const int* __restrict__ csr, const float* __restrict__ bnsc,
    const float* __restrict__ bnsh, const unsigned short* __restrict__ resb,
    unsigned short* __restrict__ outb, int N, int nb) {
    int pass = blockIdx.x / nb;
    int blk = blockIdx.x - pass * nb;
    int w = threadIdx.x >> 6, lane = threadIdx.x & 63;
    int grp = lane >> 4, l16 = lane & 15;
    int node = blk * 16 + w * 4 + grp;
    bool act = node < N;
    int start = 0, end = 0;
    float edl = 0.f;
    if (act) {
        start = row_ptr[node];
        end = row_ptr[node + 1];
        edl = ed[(size_t)pass * N + node];
    }
    const unsigned short* xh = xwb + (size_t)pass * N * 32;
    const float* esh = es + (size_t)pass * N;
    float den = 0.f, a0 = 0.f, a1 = 0.f;
    int j = start;
    int sv = (j < end) ? csr[j] : 0;
    while (j < end) {
        int svn = (j + 1 < end) ? csr[j + 1] : 0;
        unsigned uu = *(const unsigned*)(xh + (size_t)sv * 32 + l16 * 2);
        float e = esh[sv] + edl;
        e = e > 0.f ? e : 0.2f * e;
        float wg = __expf(e);
        den += wg;
        a0 = fmaf(wg, __uint_as_float(uu << 16), a0);
        a1 = fmaf(wg, __uint_as_float(uu & 0xffff0000u), a1);
        sv = svn;
        ++j;
    }
    if (act) {
        int c0 = l16 * 2;
        int cg = pass * 32 + c0;
        float inv = 1.f / den;
        float2 sc = *(const float2*)(bnsc + cg);
        float2 sh = *(const float2*)(bnsh + cg);
        size_t ro = (size_t)pass * N * 32 + (size_t)node * 32 + c0;
        unsigned ur = *(const unsigned*)(resb + ro);
        float v0 = fmaf(a0 * inv, sc.x, sh.x) + __uint_as_float(ur << 16);
        float v1 = fmaf(a1 * inv, sc.y, sh.y) + __uint_as_float(ur & 0xffff0000u);
        v0 = v0 > 0.f ? v0 : expm1f(v0);
        v1 = v1 > 0.f ? v1 : expm1f(v1);
        unsigned pk = (unsigned)f2b(v0) | ((unsigned)f2b(v1) << 16);
        *(unsigned*)(outb + ro) = pk;
    }
}

// ---------------- layer-3 agg (H=1, 40ch): wave = 3 nodes x 20 lanes ----------------
__global__ __launch_bounds__(256) void agg40_kernel(
    const unsigned short* __restrict__ xw3b, const float* __restrict__ es3,
    const float* __restrict__ ed3, const int* __restrict__ row_ptr,
    const int* __restrict__ csr, const float* __restrict__ b3,
    void* __restrict__ out, const int* __restrict__ flag, int N) {
    int w = threadIdx.x >> 6, lane = threadIdx.x & 63;
    int grp = lane < 20 ? 0 : (lane < 40 ? 1 : 2);
    int l20 = lane - grp * 20;
    bool act = (lane < 60);
    int node = (blockIdx.x * 4 + w) * 3 + grp;
    if (node >= N) act = false;
    int start = 0, end = 0;
    float edl = 0.f;
    if (act) {
        start = row_ptr[node];
        end = row_ptr[node + 1];
        edl = ed3[node];
    }
    int c0 = l20 * 2;
    float den = 0.f, a0 = 0.f, a1 = 0.f;
    int j = start;
    int sv = (j < end) ? csr[j] : 0;
    while (j < end) {
        int svn = (j + 1 < end) ? csr[j + 1] : 0;
        unsigned uu = *(const unsigned*)(xw3b + (size_t)sv * 40 + c0);
        float e = es3[sv] + edl;
        e = e > 0.f ? e : 0.2f * e;
        float wg = __expf(e);
        den += wg;
        a0 = fmaf(wg, __uint_as_float(uu << 16), a0);
        a1 = fmaf(wg, __uint_as_float(uu & 0xffff0000u), a1);
        sv = svn;
        ++j;
    }
    if (act) {
        float inv = 1.f / den;
        float v0 = a0 * inv + b3[c0];
        float v1 = a1 * inv + b3[c0 + 1];
        size_t eoff = (size_t)node * 40 + c0;
        if (*flag) {
            unsigned pk = (unsigned)f2b(v0) | ((unsigned)f2b(v1) << 16);
            *(unsigned*)((unsigned short*)out + eoff) = pk;
        } else {
            *(float2*)((float*)out + eoff) = make_float2(v0, v1);
        }
    }
}

extern "C" void kernel_launch(void* const* d_in, const int* in_sizes, int n_in,
                              void* d_out, int out_size, void* d_ws, size_t ws_size,
                              hipStream_t stream) {
    (void)n_in; (void)out_size; (void)ws_size;
    const int N = in_sizes[0] / 128;
    const int E = in_sizes[1] / 2;
    const int EPN = E + N;
    const int NB = (N + 255) / 256;
    const int CB = (EPN + 255) / 256;
    char* base = (char*)d_ws;
    size_t off = 0;
    auto alloc = [&](size_t bytes) -> char* {
        char* p = base + off;
        off = (off + bytes + 255) & ~(size_t)255;
        return p;
    };
    int* flag = (int*)alloc(4);
    int* deg = (int*)alloc((size_t)N * 4);
    int* row_ptr = (int*)alloc((size_t)(N + 1) * 4);
    int* pos = (int*)alloc((size_t)N * 4);
    int* bsum = (int*)alloc((size_t)NB * 4);
    int* boff = (int*)alloc((size_t)NB * 4);
    int* csr = (int*)alloc((size_t)EPN * 4);
    float* bnsc1 = (float*)alloc(512); float* bnsh1 = (float*)alloc(512);
    float* bnsc2 = (float*)alloc(512); float* bnsh2 = (float*)alloc(512);
    float* AS1f = (float*)alloc(512); float* AD1f = (float*)alloc(512);
    float* AS2f = (float*)alloc(512); float* AD2f = (float*)alloc(512);
    float* AS3f = (float*)alloc(256); float* AD3f = (float*)alloc(256);
    float* B3f = (float*)alloc(256);
    unsigned short* Wl1 = (unsigned short*)alloc(32768);
    unsigned short* Wl2 = (unsigned short*)alloc(32768);
    unsigned short* WlR = (unsigned short*)alloc(32768);
    unsigned short* Wl3 = (unsigned short*)alloc(12288);
    unsigned short* xb = (unsigned short*)alloc((size_t)N * 128 * 2);
    unsigned short* xwb = (unsigned short*)alloc((size_t)N * 128 * 2);  // blocked; also xw3 rowmajor
    unsigned short* h1b = (unsigned short*)alloc((size_t)N * 128 * 2);  // blocked
    unsigned short* resb = (unsigned short*)alloc((size_t)N * 128 * 2); // blocked; later h2b
    float* es = (float*)alloc((size_t)N * 4 * 4);   // [H][N]
    float* ed = (float*)alloc((size_t)N * 4 * 4);   // [H][N]

    const int* ei = (const int*)d_in[1];

    hipMemsetAsync(deg, 0, (size_t)N * 4, stream);
    detect_kernel<<<1, THREADS, 0, stream>>>((const unsigned short*)d_in[0], 4096, flag);

    InPtrs ip;
    for (int t = 0; t < 23; t++) ip.p[t] = d_in[t];
    prep_kernel<<<28 + CB + 2048, THREADS, 0, stream>>>(ip, flag, Wl1, Wl2, WlR, Wl3,
                                                        bnsc1, bnsh1, bnsc2, bnsh2,
                                                        AS1f, AD1f, AS2f, AD2f,
                                                        AS3f, AD3f, B3f, xb, N, ei, deg, E, CB);

    bsum_kernel<<<NB, 256, 0, stream>>>(deg, bsum, N);
    bscan_kernel<<<1, 1024, 0, stream>>>(bsum, boff, NB);
    scanw_kernel<<<NB, 256, 0, stream>>>(deg, boff, row_ptr, pos, N);
    scatter_kernel<<<(EPN + THREADS - 1) / THREADS, THREADS, 0, stream>>>(ei, pos, csr, E, N);

    int gemmGrid = (N + 63) / 64;
    int nb16 = (N + 15) / 16;
    int agg40Grid = (N + 11) / 12;

    // layer 1
    gemm_dual<<<gemmGrid, 256, 0, stream>>>((const unsigned short*)d_in[0], xb, flag,
                                            Wl1, WlR, AS1f, AD1f, xwb, resb, es, ed, N);
    agg128_mp<<<4 * nb16, 256, 0, stream>>>(xwb, es, ed, row_ptr, csr,
                                            bnsc1, bnsh1, resb, h1b, N, nb16);
    // layer 2 (A = h1b head-blocked: aRow=32, aKs=N*32)
    gemm_mfma<8, 4, true, true><<<gemmGrid, 256, 0, stream>>>(
        h1b, Wl2, AS2f, AD2f, xwb, 128, 128, es, ed, N, 32L, (long)N * 32);
    unsigned short* h2b = resb;  // resb free after layer-1 agg
    agg128_mp<<<4 * nb16, 256, 0, stream>>>(xwb, es, ed, row_ptr, csr,
                                            bnsc2, bnsh2, h1b, h2b, N, nb16);
    // layer 3 (A = h2b blocked; C row-major [N][40])
    gemm_mfma<3, 1, true, false><<<gemmGrid, 256, 0, stream>>>(
        h2b, Wl3, AS3f, AD3f, xwb, 40, 40, es, ed, N, 32L, (long)N * 32);
    agg40_kernel<<<agg40Grid, 256, 0, stream>>>(xwb, es, ed, row_ptr, csr, B3f,
                                                d_out, flag, N);
}

// Round 7
// 332.533 us; speedup vs baseline: 1.0802x; 1.0802x over previous
//
#include <hip/hip_runtime.h>
#include <hip/hip_bf16.h>

#define THREADS 256

typedef __attribute__((ext_vector_type(8))) short bfrag;     // 8 bf16 = 4 VGPR
typedef __attribute__((ext_vector_type(4))) float f32x4;     // MFMA accumulator

__device__ inline unsigned short f2b(float v) {
    __hip_bfloat16 b = __float2bfloat16(v);
    return *reinterpret_cast<unsigned short*>(&b);
}
__device__ inline float b2f(unsigned short u) {
    return __uint_as_float(((unsigned)u) << 16);
}
__device__ inline float rdv(const void* p, int off, bool isbf) {
    return isbf ? b2f(((const unsigned short*)p)[off]) : ((const float*)p)[off];
}

// ---------------- dtype detection (bf16 vs fp32 inputs) ----------------
__global__ void detect_kernel(const unsigned short* __restrict__ x, int n, int* flag) {
    __shared__ int cnt;
    if (threadIdx.x == 0) cnt = 0;
    __syncthreads();
    int local = 0;
    for (int i = threadIdx.x; i < n; i += THREADS) {
        unsigned ex = (x[i] >> 7) & 0xFF;
        if (ex == 0xFF || ex >= 134 || (ex > 0 && ex <= 100)) local++;
    }
    atomicAdd(&cnt, local);
    __syncthreads();
    if (threadIdx.x == 0) *flag = (cnt * 8 > n) ? 0 : 1;  // 1 = bf16
}

// ---------------- fused prep: W->frag-order, BN fold, degree count, xconv ----------------
struct InPtrs { const void* p[23]; };

__global__ void prep_kernel(InPtrs in, const int* __restrict__ flag,
                            unsigned short* __restrict__ Wl1, unsigned short* __restrict__ Wl2,
                            unsigned short* __restrict__ WlR, unsigned short* __restrict__ Wl3,
                            float* __restrict__ bnsc1, float* __restrict__ bnsh1,
                            float* __restrict__ bnsc2, float* __restrict__ bnsh2,
                            float* __restrict__ AS1f, float* __restrict__ AD1f,
                            float* __restrict__ AS2f, float* __restrict__ AD2f,
                            float* __restrict__ AS3f, float* __restrict__ AD3f,
                            float* __restrict__ B3f, unsigned short* __restrict__ xb,
                            int N, const int* __restrict__ ei, int* __restrict__ deg,
                            int E, int CB) {
    bool isbf = (*flag != 0);
    int b = blockIdx.x;
    if (b < 27) {
        // W [128,cols] raw -> bf16 fragment order
        const void* Wv; unsigned short* o; int cols, tt;
        if (b < 8)       { Wv = in.p[2];  o = Wl1; cols = 128; tt = b; }
        else if (b < 16) { Wv = in.p[6];  o = Wl2; cols = 128; tt = b - 8; }
        else if (b < 24) { Wv = in.p[14]; o = WlR; cols = 128; tt = b - 16; }
        else             { Wv = in.p[10]; o = Wl3; cols = 40;  tt = b - 24; }
        int id = tt * 256 + threadIdx.x;
        int t = id >> 8, ks = (id >> 6) & 3, l = id & 63;
        int q = l >> 4, n = l & 15;
        int c = t * 16 + n;
#pragma unroll
        for (int j = 0; j < 8; ++j) {
            int k = ks * 32 + q * 8 + j;
            float v = (c < cols) ? rdv(Wv, k * cols + c, isbf) : 0.f;
            o[id * 8 + j] = f2b(v);
        }
    } else if (b == 27) {
        int c = threadIdx.x;
        if (c < 128) {
            float s = rdv(in.p[15], c, isbf) * rsqrtf(rdv(in.p[18], c, isbf) + 1e-5f);
            bnsc1[c] = s;
            bnsh1[c] = rdv(in.p[16], c, isbf) - rdv(in.p[17], c, isbf) * s +
                       rdv(in.p[5], c, isbf) * s;
            AS1f[c] = rdv(in.p[3], c, isbf);
            AD1f[c] = rdv(in.p[4], c, isbf);
            AS2f[c] = rdv(in.p[7], c, isbf);
            AD2f[c] = rdv(in.p[8], c, isbf);
        } else {
            int d = c - 128;
            float s = rdv(in.p[19], d, isbf) * rsqrtf(rdv(in.p[22], d, isbf) + 1e-5f);
            bnsc2[d] = s;
            bnsh2[d] = rdv(in.p[20], d, isbf) - rdv(in.p[21], d, isbf) * s +
                       rdv(in.p[9], d, isbf) * s;
            if (d < 40) {
                AS3f[d] = rdv(in.p[11], d, isbf);
                AD3f[d] = rdv(in.p[12], d, isbf);
                B3f[d] = rdv(in.p[13], d, isbf);
            }
        }
    } else if (b < 28 + CB) {
        int i = (b - 28) * 256 + threadIdx.x;
        if (i < E + N) {
            int d = (i < E) ? ei[E + i] : (i - E);
            atomicAdd(&deg[d], 1);
        }
    } else {
        if (isbf) return;  // bf16 path: gemm reads d_in[0] raw
        const float* xf = (const float*)in.p[0];
        int total = N * 128;
        int stride = (gridDim.x - 28 - CB) * 256;
        for (int i = (b - 28 - CB) * 256 + threadIdx.x; i < total; i += stride)
            xb[i] = f2b(xf[i]);
    }
}

// ---------------- CSR scan stages ----------------
__global__ void bsum_kernel(const int* __restrict__ deg, int* __restrict__ bsum, int N) {
    int idx = blockIdx.x * 256 + threadIdx.x;
    int lane = threadIdx.x & 63, wv = threadIdx.x >> 6;
    int v = (idx < N) ? deg[idx] : 0;
#pragma unroll
    for (int o = 1; o < 64; o <<= 1) v += __shfl_xor(v, o, 64);
    __shared__ int ws[4];
    if (lane == 0) ws[wv] = v;
    __syncthreads();
    if (threadIdx.x == 0) bsum[blockIdx.x] = ws[0] + ws[1] + ws[2] + ws[3];
}

__global__ __launch_bounds__(1024) void bscan_kernel(const int* __restrict__ bsum,
                                                     int* __restrict__ boff, int nb) {
    __shared__ int ws[16];
    int tid = threadIdx.x, lane = tid & 63, wv = tid >> 6;
    int v = (tid < nb) ? bsum[tid] : 0;
    int sc = v;
#pragma unroll
    for (int o = 1; o < 64; o <<= 1) {
        int t = __shfl_up(sc, o, 64);
        if (lane >= o) sc += t;
    }
    if (lane == 63) ws[wv] = sc;
    __syncthreads();
    int add = 0;
#pragma unroll
    for (int k = 0; k < 16; ++k) add += (k < wv) ? ws[k] : 0;
    if (tid < nb) boff[tid] = add + sc - v;
}

__global__ void scanw_kernel(const int* __restrict__ deg, const int* __restrict__ boff,
                             int* __restrict__ row_ptr, int* __restrict__ pos, int N) {
    int idx = blockIdx.x * 256 + threadIdx.x;
    int lane = threadIdx.x & 63, wv = threadIdx.x >> 6;
    int v = (idx < N) ? deg[idx] : 0;
    int sc = v;
#pragma unroll
    for (int o = 1; o < 64; o <<= 1) {
        int t = __shfl_up(sc, o, 64);
        if (lane >= o) sc += t;
    }
    __shared__ int ws[4];
    if (lane == 63) ws[wv] = sc;
    __syncthreads();
    int add = boff[blockIdx.x];
#pragma unroll
    for (int k = 0; k < 4; ++k) add += (k < wv) ? ws[k] : 0;
    int excl = add + sc - v;
    if (idx < N) {
        pos[idx] = excl;
        row_ptr[idx + 1] = excl + v;
    }
    if (idx == 0) row_ptr[0] = 0;
}

__global__ void scatter_kernel(const int* __restrict__ ei, int* __restrict__ pos,
                               int* __restrict__ csr, int E, int N) {
    int e = blockIdx.x * THREADS + threadIdx.x;
    if (e >= E + N) return;
    int s, d;
    if (e < E) { s = ei[e]; d = ei[E + e]; }
    else { s = e - E; d = s; }
    int p = atomicAdd(&pos[d], 1);
    csr[p] = s;
}

// ---------------- MFMA GEMM: [N,128]bf16 @ [128,cols]bf16 (row-major) ----------------
template <int COLT, int HEADS, bool ES>
__global__ __launch_bounds__(256) void gemm_mfma(
    const unsigned short* __restrict__ A, const unsigned short* __restrict__ Wg,
    const float* __restrict__ as_f, const float* __restrict__ ad_f,
    unsigned short* __restrict__ out, int ldc, int cols,
    float* __restrict__ es, float* __restrict__ ed, int N) {
    __shared__ __align__(16) unsigned short Wls[COLT * 2048];
    int tid = threadIdx.x;
    {
        const float4* src = (const float4*)Wg;
        float4* dst = (float4*)Wls;
#pragma unroll
        for (int i = 0; i < COLT; ++i) dst[tid + i * 256] = src[tid + i * 256];
    }
    __syncthreads();
    int w = tid >> 6, lane = tid & 63;
    int n = lane & 15, q = lane >> 4;
    int row0 = blockIdx.x * 64 + w * 16;
    int ar = row0 + n; ar = ar < N ? ar : N - 1;   // clamp: OOB rows harmless
    f32x4 acc[COLT];
#pragma unroll
    for (int t = 0; t < COLT; ++t) acc[t] = (f32x4){0.f, 0.f, 0.f, 0.f};
    const unsigned short* arow = A + (size_t)ar * 128;
#pragma unroll
    for (int ks = 0; ks < 4; ++ks) {
        bfrag a = *reinterpret_cast<const bfrag*>(arow + ks * 32 + q * 8);
#pragma unroll
        for (int t = 0; t < COLT; ++t) {
            bfrag b = *reinterpret_cast<const bfrag*>(&Wls[((t * 4 + ks) * 64 + lane) * 8]);
            acc[t] = __builtin_amdgcn_mfma_f32_16x16x32_bf16(a, b, acc[t], 0, 0, 0);
        }
    }
    if (ES) {
        float asv[COLT], adv[COLT];
#pragma unroll
        for (int t = 0; t < COLT; ++t) {
            int c = t * 16 + n;
            asv[t] = (c < cols) ? as_f[c] : 0.f;
            adv[t] = (c < cols) ? ad_f[c] : 0.f;
        }
#pragma unroll
        for (int r = 0; r < 4; ++r) {
            float pe[HEADS], pd[HEADS];
#pragma unroll
            for (int h = 0; h < HEADS; ++h) { pe[h] = 0.f; pd[h] = 0.f; }
#pragma unroll
            for (int t = 0; t < COLT; ++t) {
                int h = (HEADS == 4) ? (t >> 1) : 0;
                pe[h] = fmaf(acc[t][r], asv[t], pe[h]);
                pd[h] = fmaf(acc[t][r], adv[t], pd[h]);
            }
#pragma unroll
            for (int h = 0; h < HEADS; ++h) {
#pragma unroll
                for (int o = 1; o < 16; o <<= 1) {
                    pe[h] += __shfl_xor(pe[h], o, 64);
                    pd[h] += __shfl_xor(pd[h], o, 64);
                }
            }
            int row = row0 + q * 4 + r;
            if (n == 0 && row < N) {
#pragma unroll
                for (int h = 0; h < HEADS; ++h) {
                    es[(size_t)row * HEADS + h] = pe[h];
                    ed[(size_t)row * HEADS + h] = pd[h];
                }
            }
        }
    }
#pragma unroll
    for (int t = 0; t < COLT; ++t) {
        int col = t * 16 + n;
        if (col < cols) {
#pragma unroll
            for (int r = 0; r < 4; ++r) {
                int row = row0 + q * 4 + r;
                if (row < N) out[(size_t)row * ldc + col] = f2b(acc[t][r]);
            }
        }
    }
}

// W1 + Wres in one pass (A read once); both outputs bf16 row-major
__global__ __launch_bounds__(256) void gemm_dual(
    const unsigned short* __restrict__ Araw, const unsigned short* __restrict__ Acvt,
    const int* __restrict__ flag,
    const unsigned short* __restrict__ Wg1, const unsigned short* __restrict__ WgR,
    const float* __restrict__ as_f, const float* __restrict__ ad_f,
    unsigned short* __restrict__ xwb, unsigned short* __restrict__ resb,
    float* __restrict__ es, float* __restrict__ ed, int N) {
    __shared__ __align__(16) unsigned short Wls[16 * 2048];
    int tid = threadIdx.x;
    {
        const float4* s1 = (const float4*)Wg1;
        const float4* s2 = (const float4*)WgR;
        float4* dst = (float4*)Wls;
#pragma unroll
        for (int i = 0; i < 8; ++i) dst[tid + i * 256] = s1[tid + i * 256];
#pragma unroll
        for (int i = 0; i < 8; ++i) dst[2048 + tid + i * 256] = s2[tid + i * 256];
    }
    const unsigned short* A = (*flag) ? Araw : Acvt;
    __syncthreads();
    int w = tid >> 6, lane = tid & 63;
    int n = lane & 15, q = lane >> 4;
    int row0 = blockIdx.x * 64 + w * 16;
    int ar = row0 + n; ar = ar < N ? ar : N - 1;
    f32x4 acc[16];
#pragma unroll
    for (int t = 0; t < 16; ++t) acc[t] = (f32x4){0.f, 0.f, 0.f, 0.f};
    const unsigned short* arow = A + (size_t)ar * 128;
#pragma unroll
    for (int ks = 0; ks < 4; ++ks) {
        bfrag a = *reinterpret_cast<const bfrag*>(arow + ks * 32 + q * 8);
#pragma unroll
        for (int t = 0; t < 8; ++t) {
            bfrag b = *reinterpret_cast<const bfrag*>(&Wls[((t * 4 + ks) * 64 + lane) * 8]);
            acc[t] = __builtin_amdgcn_mfma_f32_16x16x32_bf16(a, b, acc[t], 0, 0, 0);
        }
#pragma unroll
        for (int t = 0; t < 8; ++t) {
            bfrag b = *reinterpret_cast<const bfrag*>(&Wls[16384 + ((t * 4 + ks) * 64 + lane) * 8]);
            acc[8 + t] = __builtin_amdgcn_mfma_f32_16x16x32_bf16(a, b, acc[8 + t], 0, 0, 0);
        }
    }
    float asv[8], adv[8];
#pragma unroll
    for (int t = 0; t < 8; ++t) {
        int c = t * 16 + n;
        asv[t] = as_f[c];
        adv[t] = ad_f[c];
    }
#pragma unroll
    for (int r = 0; r < 4; ++r) {
        float pe[4] = {0.f, 0.f, 0.f, 0.f}, pd[4] = {0.f, 0.f, 0.f, 0.f};
#pragma unroll
        for (int t = 0; t < 8; ++t) {
            int h = t >> 1;
            pe[h] = fmaf(acc[t][r], asv[t], pe[h]);
            pd[h] = fmaf(acc[t][r], adv[t], pd[h]);
        }
#pragma unroll
        for (int h = 0; h < 4; ++h) {
#pragma unroll
            for (int o = 1; o < 16; o <<= 1) {
                pe[h] += __shfl_xor(pe[h], o, 64);
                pd[h] += __shfl_xor(pd[h], o, 64);
            }
        }
        int row = row0 + q * 4 + r;
        if (n == 0 && row < N) {
#pragma unroll
            for (int h = 0; h < 4; ++h) {
                es[(size_t)row * 4 + h] = pe[h];
                ed[(size_t)row * 4 + h] = pd[h];
            }
        }
    }
#pragma unroll
    for (int t = 0; t < 8; ++t) {
        int col = t * 16 + n;
#pragma unroll
        for (int r = 0; r < 4; ++r) {
            int row = row0 + q * 4 + r;
            if (row < N) {
                xwb[(size_t)row * 128 + col] = f2b(acc[t][r]);
                resb[(size_t)row * 128 + col] = f2b(acc[8 + t][r]);
            }
        }
    }
}

// ---------------- agg layers 1-2 + fused BN/bias/residual/ELU ----------------
// wave/node; 16-edge chunks; row-gathers preloaded into registers but GUARDED
// by wave-uniform u<cnt (readfirstlane) -> exact traffic, up to 16 in flight.
__global__ __launch_bounds__(256) void agg128_fused(
    const unsigned short* __restrict__ xwb, const float* __restrict__ es,
    const float* __restrict__ ed, const int* __restrict__ row_ptr,
    const int* __restrict__ csr, const float* __restrict__ bnsc,
    const float* __restrict__ bnsh, const unsigned short* __restrict__ resb,
    unsigned short* __restrict__ outb, int N) {
    int w = threadIdx.x >> 6, lane = threadIdx.x & 63;
    int node = blockIdx.x * 4 + w;
    if (node >= N) return;
    int h = lane >> 4;
    int i16 = lane & 15;
    int base = lane & 48;
    int c0 = lane * 2;
    float edl = ed[node * 4 + h];
    int start = __builtin_amdgcn_readfirstlane(row_ptr[node]);
    int end = __builtin_amdgcn_readfirstlane(row_ptr[node + 1]);
    float den = 0.f, a0 = 0.f, a1 = 0.f;
    for (int jb = start; jb < end; jb += 16) {
        int cnt = end - jb; cnt = cnt < 16 ? cnt : 16;
        cnt = __builtin_amdgcn_readfirstlane(cnt);
        int idx = jb + i16;
        int sv = csr[idx < end ? idx : end - 1];
        unsigned uu[16];
#pragma unroll
        for (int u = 0; u < 16; ++u) {
            if (u < cnt) {
                int s = __shfl(sv, u, 64);
                uu[u] = *(const unsigned*)(xwb + (size_t)s * 128 + c0);
            }
        }
        float wgl = 0.f;
        if (i16 < cnt) {
            float e = es[sv * 4 + h] + edl;
            e = e > 0.f ? e : 0.2f * e;
            wgl = __expf(e);
        }
        float d = wgl;
        d += __shfl_xor(d, 1, 64);
        d += __shfl_xor(d, 2, 64);
        d += __shfl_xor(d, 4, 64);
        d += __shfl_xor(d, 8, 64);
        den += d;
#pragma unroll
        for (int u = 0; u < 16; ++u) {
            if (u < cnt) {
                float wg = __shfl(wgl, base + u, 64);
                a0 = fmaf(wg, __uint_as_float(uu[u] << 16), a0);
                a1 = fmaf(wg, __uint_as_float(uu[u] & 0xffff0000u), a1);
            }
        }
    }
    float inv = 1.f / den;
    float2 sc = *(const float2*)(bnsc + c0);
    float2 sh = *(const float2*)(bnsh + c0);
    unsigned ur = *(const unsigned*)(resb + (size_t)node * 128 + c0);
    float v0 = fmaf(a0 * inv, sc.x, sh.x) + __uint_as_float(ur << 16);
    float v1 = fmaf(a1 * inv, sc.y, sh.y) + __uint_as_float(ur & 0xffff0000u);
    v0 = v0 > 0.f ? v0 : expm1f(v0);
    v1 = v1 > 0.f ? v1 : expm1f(v1);
    unsigned pk = (unsigned)f2b(v0) | ((unsigned)f2b(v1) << 16);
    *(unsigned*)(outb + (size_t)node * 128 + c0) = pk;
}

// ---------------- layer-3 agg (H=1, 40ch): 3 edge-groups x 20 lanes, guarded preloads ----
__global__ __launch_bounds__(256) void agg40_kernel(
    const unsigned short* __restrict__ xw3b, const float* __restrict__ es3,
    const float* __restrict__ ed3, const int* __restrict__ row_ptr,
    const int* __restrict__ csr, const float* __restrict__ b3,
    void* __restrict__ out, const int* __restrict__ flag, int N) {
    int w = threadIdx.x >> 6, lane = threadIdx.x & 63;
    int node = blockIdx.x * 4 + w;
    if (node >= N) return;
    int i16 = lane & 15;
    int g = lane >= 40 ? 2 : (lane >= 20 ? 1 : 0);
    int cp = lane - g * 20;
    int c0 = cp * 2; c0 = c0 > 38 ? 38 : c0;
    float edl = ed3[node];
    int start = __builtin_amdgcn_readfirstlane(row_ptr[node]);
    int end = __builtin_amdgcn_readfirstlane(row_ptr[node + 1]);
    float den = 0.f, a0 = 0.f, a1 = 0.f;
    for (int jb = start; jb < end; jb += 16) {
        int cnt = end - jb; cnt = cnt < 16 ? cnt : 16;
        cnt = __builtin_amdgcn_readfirstlane(cnt);
        int idx = jb + i16;
        int sv = csr[idx < end ? idx : end - 1];
        unsigned uu[6];
#pragma unroll
        for (int t = 0; t < 6; ++t) {
            int slot = 3 * t + g;
            if (slot < cnt) {
                int s = __shfl(sv, slot, 64);
                uu[t] = *(const unsigned*)(xw3b + (size_t)s * 40 + c0);
            }
        }
        float wgl = 0.f;
        if (i16 < cnt) {
            float e = es3[sv] + edl;
            e = e > 0.f ? e : 0.2f * e;
            wgl = __expf(e);
        }
        float d = wgl;
        d += __shfl_xor(d, 1, 64);
        d += __shfl_xor(d, 2, 64);
        d += __shfl_xor(d, 4, 64);
        d += __shfl_xor(d, 8, 64);
        den += d;
#pragma unroll
        for (int t = 0; t < 6; ++t) {
            int slot = 3 * t + g;
            if (slot < cnt) {
                float wg = __shfl(wgl, slot, 64);
                a0 = fmaf(wg, __uint_as_float(uu[t] << 16), a0);
                a1 = fmaf(wg, __uint_as_float(uu[t] & 0xffff0000u), a1);
            }
        }
    }
    float t0 = __shfl(a0, (lane + 20) & 63, 64);
    float t1 = __shfl(a0, (lane + 40) & 63, 64);
    float u0 = __shfl(a1, (lane + 20) & 63, 64);
    float u1 = __shfl(a1, (lane + 40) & 63, 64);
    a0 += t0 + t1;
    a1 += u0 + u1;
    if (lane < 20) {
        float inv = 1.f / den;
        float v0 = a0 * inv + b3[c0];
        float v1 = a1 * inv + b3[c0 + 1];
        size_t eoff = (size_t)node * 40 + c0;
        if (*flag) {
            unsigned pk = (unsigned)f2b(v0) | ((unsigned)f2b(v1) << 16);
            *(unsigned*)((unsigned short*)out + eoff) = pk;
        } else {
            *(float2*)((float*)out + eoff) = make_float2(v0, v1);
        }
    }
}

extern "C" void kernel_launch(void* const* d_in, const int* in_sizes, int n_in,
                              void* d_out, int out_size, void* d_ws, size_t ws_size,
                              hipStream_t stream) {
    (void)n_in; (void)out_size; (void)ws_size;
    const int N = in_sizes[0] / 128;
    const int E = in_sizes[1] / 2;
    const int EPN = E + N;
    const int NB = (N + 255) / 256;
    const int CB = (EPN + 255) / 256;
    char* base = (char*)d_ws;
    size_t off = 0;
    auto alloc = [&](size_t bytes) -> char* {
        char* p = base + off;
        off = (off + bytes + 255) & ~(size_t)255;
        return p;
    };
    int* flag = (int*)alloc(4);
    int* deg = (int*)alloc((size_t)N * 4);
    int* row_ptr = (int*)alloc((size_t)(N + 1) * 4);
    int* pos = (int*)alloc((size_t)N * 4);
    int* bsum = (int*)alloc((size_t)NB * 4);
    int* boff = (int*)alloc((size_t)NB * 4);
    int* csr = (int*)alloc((size_t)EPN * 4);
    float* bnsc1 = (float*)alloc(512); float* bnsh1 = (float*)alloc(512);
    float* bnsc2 = (float*)alloc(512); float* bnsh2 = (float*)alloc(512);
    float* AS1f = (float*)alloc(512); float* AD1f = (float*)alloc(512);
    float* AS2f = (float*)alloc(512); float* AD2f = (float*)alloc(512);
    float* AS3f = (float*)alloc(256); float* AD3f = (float*)alloc(256);
    float* B3f = (float*)alloc(256);
    unsigned short* Wl1 = (unsigned short*)alloc(32768);
    unsigned short* Wl2 = (unsigned short*)alloc(32768);
    unsigned short* WlR = (unsigned short*)alloc(32768);
    unsigned short* Wl3 = (unsigned short*)alloc(12288);
    unsigned short* xb = (unsigned short*)alloc((size_t)N * 128 * 2);
    unsigned short* xwb = (unsigned short*)alloc((size_t)N * 128 * 2);  // also xw3
    unsigned short* h1b = (unsigned short*)alloc((size_t)N * 128 * 2);
    unsigned short* resb = (unsigned short*)alloc((size_t)N * 128 * 2); // later h2b
    float* es = (float*)alloc((size_t)N * 4 * 4);   // [node*4+h]
    float* ed = (float*)alloc((size_t)N * 4 * 4);

    const int* ei = (const int*)d_in[1];

    hipMemsetAsync(deg, 0, (size_t)N * 4, stream);
    detect_kernel<<<1, THREADS, 0, stream>>>((const unsigned short*)d_in[0], 4096, flag);

    InPtrs ip;
    for (int t = 0; t < 23; t++) ip.p[t] = d_in[t];
    prep_kernel<<<28 + CB + 1024, THREADS, 0, stream>>>(ip, flag, Wl1, Wl2, WlR, Wl3,
                                                        bnsc1, bnsh1, bnsc2, bnsh2,
                                                        AS1f, AD1f, AS2f, AD2f,
                                                        AS3f, AD3f, B3f, xb, N, ei, deg, E, CB);

    bsum_kernel<<<NB, 256, 0, stream>>>(deg, bsum, N);
    bscan_kernel<<<1, 1024, 0, stream>>>(bsum, boff, NB);
    scanw_kernel<<<NB, 256, 0, stream>>>(deg, boff, row_ptr, pos, N);
    scatter_kernel<<<(EPN + THREADS - 1) / THREADS, THREADS, 0, stream>>>(ei, pos, csr, E, N);

    int gemmGrid = (N + 63) / 64;
    int aggGrid = (N + 3) / 4;

    // layer 1 (W1 + Wres fused GEMM; BN/bias/res/ELU fused into agg epilogue)
    gemm_dual<<<gemmGrid, 256, 0, stream>>>((const unsigned short*)d_in[0], xb, flag,
                                            Wl1, WlR, AS1f, AD1f, xwb, resb, es, ed, N);
    agg128_fused<<<aggGrid, 256, 0, stream>>>(xwb, es, ed, row_ptr, csr,
                                              bnsc1, bnsh1, resb, h1b, N);
    // layer 2
    gemm_mfma<8, 4, true><<<gemmGrid, 256, 0, stream>>>(
        h1b, Wl2, AS2f, AD2f, xwb, 128, 128, es, ed, N);
    unsigned short* h2b = resb;  // resb free after layer-1 agg
    agg128_fused<<<aggGrid, 256, 0, stream>>>(xwb, es, ed, row_ptr, csr,
                                              bnsc2, bnsh2, h1b, h2b, N);
    // layer 3
    gemm_mfma<3, 1, true><<<gemmGrid, 256, 0, stream>>>(
        h2b, Wl3, AS3f, AD3f, xwb, 40, 40, es, ed, N);
    agg40_kernel<<<aggGrid, 256, 0, stream>>>(xwb, es, ed, row_ptr, csr, B3f,
                                              d_out, flag, N);
}

// Round 8
// 326.664 us; speedup vs baseline: 1.0996x; 1.0180x over previous
//
#include <hip/hip_runtime.h>
#include <hip/hip_bf16.h>

#define THREADS 256

typedef __attribute__((ext_vector_type(8))) short bfrag;     // 8 bf16 = 4 VGPR
typedef __attribute__((ext_vector_type(4))) float f32x4;     // MFMA accumulator

__device__ inline unsigned short f2b(float v) {
    __hip_bfloat16 b = __float2bfloat16(v);
    return *reinterpret_cast<unsigned short*>(&b);
}
__device__ inline float b2f(unsigned short u) {
    return __uint_as_float(((unsigned)u) << 16);
}
__device__ inline float rdv(const void* p, int off, bool isbf) {
    return isbf ? b2f(((const unsigned short*)p)[off]) : ((const float*)p)[off];
}

// ---------------- dtype detection (bf16 vs fp32 inputs) ----------------
__global__ void detect_kernel(const unsigned short* __restrict__ x, int n, int* flag) {
    __shared__ int cnt;
    if (threadIdx.x == 0) cnt = 0;
    __syncthreads();
    int local = 0;
    for (int i = threadIdx.x; i < n; i += THREADS) {
        unsigned ex = (x[i] >> 7) & 0xFF;
        if (ex == 0xFF || ex >= 134 || (ex > 0 && ex <= 100)) local++;
    }
    atomicAdd(&cnt, local);
    __syncthreads();
    if (threadIdx.x == 0) *flag = (cnt * 8 > n) ? 0 : 1;  // 1 = bf16
}

// ---------------- fused prep: W->frag-order, BN fold, degree count, xconv ----------------
struct InPtrs { const void* p[23]; };

__global__ void prep_kernel(InPtrs in, const int* __restrict__ flag,
                            unsigned short* __restrict__ Wl1, unsigned short* __restrict__ Wl2,
                            unsigned short* __restrict__ WlR, unsigned short* __restrict__ Wl3,
                            float* __restrict__ bnsc1, float* __restrict__ bnsh1,
                            float* __restrict__ bnsc2, float* __restrict__ bnsh2,
                            float* __restrict__ AS1f, float* __restrict__ AD1f,
                            float* __restrict__ AS2f, float* __restrict__ AD2f,
                            float* __restrict__ AS3f, float* __restrict__ AD3f,
                            float* __restrict__ B3f, unsigned short* __restrict__ xb,
                            int N, const int* __restrict__ ei, int* __restrict__ deg,
                            int E, int CB) {
    bool isbf = (*flag != 0);
    int b = blockIdx.x;
    if (b < 27) {
        // W [128,cols] raw -> bf16 fragment order
        const void* Wv; unsigned short* o; int cols, tt;
        if (b < 8)       { Wv = in.p[2];  o = Wl1; cols = 128; tt = b; }
        else if (b < 16) { Wv = in.p[6];  o = Wl2; cols = 128; tt = b - 8; }
        else if (b < 24) { Wv = in.p[14]; o = WlR; cols = 128; tt = b - 16; }
        else             { Wv = in.p[10]; o = Wl3; cols = 40;  tt = b - 24; }
        int id = tt * 256 + threadIdx.x;
        int t = id >> 8, ks = (id >> 6) & 3, l = id & 63;
        int q = l >> 4, n = l & 15;
        int c = t * 16 + n;
#pragma unroll
        for (int j = 0; j < 8; ++j) {
            int k = ks * 32 + q * 8 + j;
            float v = (c < cols) ? rdv(Wv, k * cols + c, isbf) : 0.f;
            o[id * 8 + j] = f2b(v);
        }
    } else if (b == 27) {
        int c = threadIdx.x;
        if (c < 128) {
            float s = rdv(in.p[15], c, isbf) * rsqrtf(rdv(in.p[18], c, isbf) + 1e-5f);
            bnsc1[c] = s;
            bnsh1[c] = rdv(in.p[16], c, isbf) - rdv(in.p[17], c, isbf) * s +
                       rdv(in.p[5], c, isbf) * s;
            AS1f[c] = rdv(in.p[3], c, isbf);
            AD1f[c] = rdv(in.p[4], c, isbf);
            AS2f[c] = rdv(in.p[7], c, isbf);
            AD2f[c] = rdv(in.p[8], c, isbf);
        } else {
            int d = c - 128;
            float s = rdv(in.p[19], d, isbf) * rsqrtf(rdv(in.p[22], d, isbf) + 1e-5f);
            bnsc2[d] = s;
            bnsh2[d] = rdv(in.p[20], d, isbf) - rdv(in.p[21], d, isbf) * s +
                       rdv(in.p[9], d, isbf) * s;
            if (d < 40) {
                AS3f[d] = rdv(in.p[11], d, isbf);
                AD3f[d] = rdv(in.p[12], d, isbf);
                B3f[d] = rdv(in.p[13], d, isbf);
            }
        }
    } else if (b < 28 + CB) {
        int i = (b - 28) * 256 + threadIdx.x;
        if (i < E + N) {
            int d = (i < E) ? ei[E + i] : (i - E);
            atomicAdd(&deg[d], 1);
        }
    } else {
        if (isbf) return;  // bf16 path: gemm reads d_in[0] raw
        const float* xf = (const float*)in.p[0];
        int total = N * 128;
        int stride = (gridDim.x - 28 - CB) * 256;
        for (int i = (b - 28 - CB) * 256 + threadIdx.x; i < total; i += stride)
            xb[i] = f2b(xf[i]);
    }
}

// ---------------- CSR scan stages ----------------
__global__ void bsum_kernel(const int* __restrict__ deg, int* __restrict__ bsum, int N) {
    int idx = blockIdx.x * 256 + threadIdx.x;
    int lane = threadIdx.x & 63, wv = threadIdx.x >> 6;
    int v = (idx < N) ? deg[idx] : 0;
#pragma unroll
    for (int o = 1; o < 64; o <<= 1) v += __shfl_xor(v, o, 64);
    __shared__ int ws[4];
    if (lane == 0) ws[wv] = v;
    __syncthreads();
    if (threadIdx.x == 0) bsum[blockIdx.x] = ws[0] + ws[1] + ws[2] + ws[3];
}

__global__ __launch_bounds__(1024) void bscan_kernel(const int* __restrict__ bsum,
                                                     int* __restrict__ boff, int nb) {
    __shared__ int ws[16];
    int tid = threadIdx.x, lane = tid & 63, wv = tid >> 6;
    int v = (tid < nb) ? bsum[tid] : 0;
    int sc = v;
#pragma unroll
    for (int o = 1; o < 64; o <<= 1) {
        int t = __shfl_up(sc, o, 64);
        if (lane >= o) sc += t;
    }
    if (lane == 63) ws[wv] = sc;
    __syncthreads();
    int add = 0;
#pragma unroll
    for (int k = 0; k < 16; ++k) add += (k < wv) ? ws[k] : 0;
    if (tid < nb) boff[tid] = add + sc - v;
}

__global__ void scanw_kernel(const int* __restrict__ deg, const int* __restrict__ boff,
                             int* __restrict__ row_ptr, int* __restrict__ pos, int N) {
    int idx = blockIdx.x * 256 + threadIdx.x;
    int lane = threadIdx.x & 63, wv = threadIdx.x >> 6;
    int v = (idx < N) ? deg[idx] : 0;
    int sc = v;
#pragma unroll
    for (int o = 1; o < 64; o <<= 1) {
        int t = __shfl_up(sc, o, 64);
        if (lane >= o) sc += t;
    }
    __shared__ int ws[4];
    if (lane == 63) ws[wv] = sc;
    __syncthreads();
    int add = boff[blockIdx.x];
#pragma unroll
    for (int k = 0; k < 4; ++k) add += (k < wv) ? ws[k] : 0;
    int excl = add + sc - v;
    if (idx < N) {
        pos[idx] = excl;
        row_ptr[idx + 1] = excl + v;
    }
    if (idx == 0) row_ptr[0] = 0;
}

__global__ void scatter_kernel(const int* __restrict__ ei, int* __restrict__ pos,
                               int* __restrict__ csr, int E, int N) {
    int e = blockIdx.x * THREADS + threadIdx.x;
    if (e >= E + N) return;
    int s, d;
    if (e < E) { s = ei[e]; d = ei[E + e]; }
    else { s = e - E; d = s; }
    int p = atomicAdd(&pos[d], 1);
    csr[p] = s;
}

// ---------------- MFMA GEMM: [N,128]bf16 @ [128,cols]bf16 ----------------
// A addressing: frag = A + ar*aRow + ks*aKs + q*8 (row-major: aRow=128,aKs=32;
// head-blocked [4][N][32]: aRow=32, aKs=N*32).
// C: CBLK -> head-blocked [col>>5][N][32]; else row-major ldc. es/ed stored [H][N].
template <int COLT, int HEADS, bool ES, bool CBLK>
__global__ __launch_bounds__(256) void gemm_mfma(
    const unsigned short* __restrict__ A, const unsigned short* __restrict__ Wg,
    const float* __restrict__ as_f, const float* __restrict__ ad_f,
    unsigned short* __restrict__ out, int ldc, int cols,
    float* __restrict__ es, float* __restrict__ ed, int N,
    long aRow, long aKs) {
    __shared__ __align__(16) unsigned short Wls[COLT * 2048];
    int tid = threadIdx.x;
    {
        const float4* src = (const float4*)Wg;
        float4* dst = (float4*)Wls;
#pragma unroll
        for (int i = 0; i < COLT; ++i) dst[tid + i * 256] = src[tid + i * 256];
    }
    __syncthreads();
    int w = tid >> 6, lane = tid & 63;
    int n = lane & 15, q = lane >> 4;
    int row0 = blockIdx.x * 64 + w * 16;
    int ar = row0 + n; ar = ar < N ? ar : N - 1;   // clamp: OOB rows harmless
    f32x4 acc[COLT];
#pragma unroll
    for (int t = 0; t < COLT; ++t) acc[t] = (f32x4){0.f, 0.f, 0.f, 0.f};
    const unsigned short* abase = A + (size_t)ar * aRow;
#pragma unroll
    for (int ks = 0; ks < 4; ++ks) {
        bfrag a = *reinterpret_cast<const bfrag*>(abase + (size_t)ks * aKs + q * 8);
#pragma unroll
        for (int t = 0; t < COLT; ++t) {
            bfrag b = *reinterpret_cast<const bfrag*>(&Wls[((t * 4 + ks) * 64 + lane) * 8]);
            acc[t] = __builtin_amdgcn_mfma_f32_16x16x32_bf16(a, b, acc[t], 0, 0, 0);
        }
    }
    if (ES) {
        float asv[COLT], adv[COLT];
#pragma unroll
        for (int t = 0; t < COLT; ++t) {
            int c = t * 16 + n;
            asv[t] = (c < cols) ? as_f[c] : 0.f;
            adv[t] = (c < cols) ? ad_f[c] : 0.f;
        }
#pragma unroll
        for (int r = 0; r < 4; ++r) {
            float pe[HEADS], pd[HEADS];
#pragma unroll
            for (int h = 0; h < HEADS; ++h) { pe[h] = 0.f; pd[h] = 0.f; }
#pragma unroll
            for (int t = 0; t < COLT; ++t) {
                int h = (HEADS == 4) ? (t >> 1) : 0;
                pe[h] = fmaf(acc[t][r], asv[t], pe[h]);
                pd[h] = fmaf(acc[t][r], adv[t], pd[h]);
            }
#pragma unroll
            for (int h = 0; h < HEADS; ++h) {
#pragma unroll
                for (int o = 1; o < 16; o <<= 1) {
                    pe[h] += __shfl_xor(pe[h], o, 64);
                    pd[h] += __shfl_xor(pd[h], o, 64);
                }
            }
            int row = row0 + q * 4 + r;
            if (n == 0 && row < N) {
#pragma unroll
                for (int h = 0; h < HEADS; ++h) {
                    es[(size_t)h * N + row] = pe[h];
                    ed[(size_t)h * N + row] = pd[h];
                }
            }
        }
    }
#pragma unroll
    for (int t = 0; t < COLT; ++t) {
        int col = t * 16 + n;
        if (col < cols) {
#pragma unroll
            for (int r = 0; r < 4; ++r) {
                int row = row0 + q * 4 + r;
                if (row < N) {
                    if (CBLK)
                        out[(size_t)(col >> 5) * N * 32 + (size_t)row * 32 + (col & 31)] =
                            f2b(acc[t][r]);
                    else
                        out[(size_t)row * ldc + col] = f2b(acc[t][r]);
                }
            }
        }
    }
}

// W1 + Wres in one pass (A read once); C outputs head-blocked bf16; es/ed [H][N]
__global__ __launch_bounds__(256) void gemm_dual(
    const unsigned short* __restrict__ Araw, const unsigned short* __restrict__ Acvt,
    const int* __restrict__ flag,
    const unsigned short* __restrict__ Wg1, const unsigned short* __restrict__ WgR,
    const float* __restrict__ as_f, const float* __restrict__ ad_f,
    unsigned short* __restrict__ xwb, unsigned short* __restrict__ resb,
    float* __restrict__ es, float* __restrict__ ed, int N) {
    __shared__ __align__(16) unsigned short Wls[16 * 2048];
    int tid = threadIdx.x;
    {
        const float4* s1 = (const float4*)Wg1;
        const float4* s2 = (const float4*)WgR;
        float4* dst = (float4*)Wls;
#pragma unroll
        for (int i = 0; i < 8; ++i) dst[tid + i * 256] = s1[tid + i * 256];
#pragma unroll
        for (int i = 0; i < 8; ++i) dst[2048 + tid + i * 256] = s2[tid + i * 256];
    }
    const unsigned short* A = (*flag) ? Araw : Acvt;
    __syncthreads();
    int w = tid >> 6, lane = tid & 63;
    int n = lane & 15, q = lane >> 4;
    int row0 = blockIdx.x * 64 + w * 16;
    int ar = row0 + n; ar = ar < N ? ar : N - 1;
    f32x4 acc[16];
#pragma unroll
    for (int t = 0; t < 16; ++t) acc[t] = (f32x4){0.f, 0.f, 0.f, 0.f};
    const unsigned short* arow = A + (size_t)ar * 128;
#pragma unroll
    for (int ks = 0; ks < 4; ++ks) {
        bfrag a = *reinterpret_cast<const bfrag*>(arow + ks * 32 + q * 8);
#pragma unroll
        for (int t = 0; t < 8; ++t) {
            bfrag b = *reinterpret_cast<const bfrag*>(&Wls[((t * 4 + ks) * 64 + lane) * 8]);
            acc[t] = __builtin_amdgcn_mfma_f32_16x16x32_bf16(a, b, acc[t], 0, 0, 0);
        }
#pragma unroll
        for (int t = 0; t < 8; ++t) {
            bfrag b = *reinterpret_cast<const bfrag*>(&Wls[16384 + ((t * 4 + ks) * 64 + lane) * 8]);
            acc[8 + t] = __builtin_amdgcn_mfma_f32_16x16x32_bf16(a, b, acc[8 + t], 0, 0, 0);
        }
    }
    float asv[8], adv[8];
#pragma unroll
    for (int t = 0; t < 8; ++t) {
        int c = t * 16 + n;
        asv[t] = as_f[c];
        adv[t] = ad_f[c];
    }
#pragma unroll
    for (int r = 0; r < 4; ++r) {
        float pe[4] = {0.f, 0.f, 0.f, 0.f}, pd[4] = {0.f, 0.f, 0.f, 0.f};
#pragma unroll
        for (int t = 0; t < 8; ++t) {
            int h = t >> 1;
            pe[h] = fmaf(acc[t][r], asv[t], pe[h]);
            pd[h] = fmaf(acc[t][r], adv[t], pd[h]);
        }
#pragma unroll
        for (int h = 0; h < 4; ++h) {
#pragma unroll
            for (int o = 1; o < 16; o <<= 1) {
                pe[h] += __shfl_xor(pe[h], o, 64);
                pd[h] += __shfl_xor(pd[h], o, 64);
            }
        }
        int row = row0 + q * 4 + r;
        if (n == 0 && row < N) {
#pragma unroll
            for (int h = 0; h < 4; ++h) {
                es[(size_t)h * N + row] = pe[h];
                ed[(size_t)h * N + row] = pd[h];
            }
        }
    }
#pragma unroll
    for (int t = 0; t < 8; ++t) {
        int col = t * 16 + n;
#pragma unroll
        for (int r = 0; r < 4; ++r) {
            int row = row0 + q * 4 + r;
            if (row < N) {
                size_t o = (size_t)(col >> 5) * N * 32 + (size_t)row * 32 + (col & 31);
                xwb[o] = f2b(acc[t][r]);
                resb[o] = f2b(acc[8 + t][r]);
            }
        }
    }
}

// ---------------- agg layers 1-2: ONE HEAD per launch (L2-resident 3.2MB slice) ----------
// 4 sequential launches. Wave = 2 nodes x 32 lanes; per 16-edge chunk each lane
// preloads 8 rows UNCONDITIONALLY (no branches around loads -> max MLP; dup
// slots get weight 0). Fused BN/bias/residual/ELU epilogue.
__global__ __launch_bounds__(256) void agg128_pass(
    const unsigned short* __restrict__ xwb, const float* __restrict__ es,
    const float* __restrict__ ed, const int* __restrict__ row_ptr,
    const int* __restrict__ csr, const float* __restrict__ bnsc,
    const float* __restrict__ bnsh, const unsigned short* __restrict__ resb,
    unsigned short* __restrict__ outb, int N, int pass) {
    int tid = threadIdx.x;
    int w = tid >> 6, lane = tid & 63;
    int half = lane >> 5, grp2 = (lane >> 4) & 1, l16 = lane & 15;
    int node = (blockIdx.x * 4 + w) * 2 + half;
    if (node >= N) return;
    const unsigned short* xh = xwb + (size_t)pass * N * 32;
    const float* esh = es + (size_t)pass * N;
    float edl = ed[(size_t)pass * N + node];
    int start = row_ptr[node], end = row_ptr[node + 1];
    int c0 = l16 * 2;
    float den = 0.f, a0 = 0.f, a1 = 0.f;
    for (int jb = start; jb < end; jb += 16) {
        int cnt = end - jb; cnt = cnt < 16 ? cnt : 16;
        int idx = jb + l16;
        int sv = csr[idx < end ? idx : end - 1];
        unsigned uu[8];
#pragma unroll
        for (int u = 0; u < 8; ++u) {
            int s = __shfl(sv, half * 32 + grp2 * 8 + u, 64);
            uu[u] = *(const unsigned*)(xh + (size_t)s * 32 + c0);
        }
        float wgl = 0.f;
        if (l16 < cnt) {
            float e = esh[sv] + edl;
            e = e > 0.f ? e : 0.2f * e;
            wgl = __expf(e);
        }
        float d = wgl;
        d += __shfl_xor(d, 1, 64);
        d += __shfl_xor(d, 2, 64);
        d += __shfl_xor(d, 4, 64);
        d += __shfl_xor(d, 8, 64);
        den += d;
#pragma unroll
        for (int u = 0; u < 8; ++u) {
            float wg = __shfl(wgl, half * 32 + grp2 * 8 + u, 64);  // 0 for padded slots
            a0 = fmaf(wg, __uint_as_float(uu[u] << 16), a0);
            a1 = fmaf(wg, __uint_as_float(uu[u] & 0xffff0000u), a1);
        }
    }
    a0 += __shfl_xor(a0, 16, 64);
    a1 += __shfl_xor(a1, 16, 64);
    if (grp2 == 0) {
        int cg = pass * 32 + c0;
        float inv = 1.f / den;
        float2 sc = *(const float2*)(bnsc + cg);
        float2 sh = *(const float2*)(bnsh + cg);
        size_t ro = ((size_t)pass * N + node) * 32 + c0;
        unsigned ur = *(const unsigned*)(resb + ro);
        float v0 = fmaf(a0 * inv, sc.x, sh.x) + __uint_as_float(ur << 16);
        float v1 = fmaf(a1 * inv, sc.y, sh.y) + __uint_as_float(ur & 0xffff0000u);
        v0 = v0 > 0.f ? v0 : expm1f(v0);
        v1 = v1 > 0.f ? v1 : expm1f(v1);
        unsigned pk = (unsigned)f2b(v0) | ((unsigned)f2b(v1) << 16);
        *(unsigned*)(outb + ro) = pk;
    }
}

// ---------------- layer-3 agg (H=1, 40ch): round-5 form (unconditional preloads) ------
__global__ __launch_bounds__(256) void agg40_kernel(
    const unsigned short* __restrict__ xw3b, const float* __restrict__ es3,
    const float* __restrict__ ed3, const int* __restrict__ row_ptr,
    const int* __restrict__ csr, const float* __restrict__ b3,
    void* __restrict__ out, const int* __restrict__ flag, int N) {
    int w = threadIdx.x >> 6, lane = threadIdx.x & 63;
    int node = blockIdx.x * 4 + w;
    if (node >= N) return;
    int i16 = lane & 15;
    int g = lane >= 40 ? 2 : (lane >= 20 ? 1 : 0);
    int cp = lane - g * 20;
    int c0 = cp * 2; c0 = c0 > 38 ? 38 : c0;
    float edl = ed3[node];
    int start = row_ptr[node], end = row_ptr[node + 1];
    float den = 0.f, a0 = 0.f, a1 = 0.f;
    for (int jb = start; jb < end; jb += 16) {
        int cnt = end - jb; cnt = cnt < 16 ? cnt : 16;
        int sv = csr[jb + (i16 < cnt ? i16 : 0)];
        unsigned uu[6];
#pragma unroll
        for (int t = 0; t < 6; ++t) {
            int slot = 3 * t + g; slot = slot < 15 ? slot : 15;
            int s = __shfl(sv, slot, 64);
            uu[t] = *(const unsigned*)(xw3b + (size_t)s * 40 + c0);
        }
        float wgl = 0.f;
        if (i16 < cnt) {
            float e = es3[sv] + edl;
            e = e > 0.f ? e : 0.2f * e;
            wgl = __expf(e);
        }
        float d = wgl;
        d += __shfl_xor(d, 1, 64);
        d += __shfl_xor(d, 2, 64);
        d += __shfl_xor(d, 4, 64);
        d += __shfl_xor(d, 8, 64);
        den += d;
#pragma unroll
        for (int t = 0; t < 6; ++t) {
            int slot = 3 * t + g;
            int sl = slot < 15 ? slot : 15;
            float wg = __shfl(wgl, sl, 64);
            if (slot >= cnt) wg = 0.f;
            a0 = fmaf(wg, __uint_as_float(uu[t] << 16), a0);
            a1 = fmaf(wg, __uint_as_float(uu[t] & 0xffff0000u), a1);
        }
    }
    float t0 = __shfl(a0, (lane + 20) & 63, 64);
    float t1 = __shfl(a0, (lane + 40) & 63, 64);
    float u0 = __shfl(a1, (lane + 20) & 63, 64);
    float u1 = __shfl(a1, (lane + 40) & 63, 64);
    a0 += t0 + t1;
    a1 += u0 + u1;
    if (lane < 20) {
        float inv = 1.f / den;
        float v0 = a0 * inv + b3[c0];
        float v1 = a1 * inv + b3[c0 + 1];
        size_t eoff = (size_t)node * 40 + c0;
        if (*flag) {
            unsigned pk = (unsigned)f2b(v0) | ((unsigned)f2b(v1) << 16);
            *(unsigned*)((unsigned short*)out + eoff) = pk;
        } else {
            *(float2*)((float*)out + eoff) = make_float2(v0, v1);
        }
    }
}

extern "C" void kernel_launch(void* const* d_in, const int* in_sizes, int n_in,
                              void* d_out, int out_size, void* d_ws, size_t ws_size,
                              hipStream_t stream) {
    (void)n_in; (void)out_size; (void)ws_size;
    const int N = in_sizes[0] / 128;
    const int E = in_sizes[1] / 2;
    const int EPN = E + N;
    const int NB = (N + 255) / 256;
    const int CB = (EPN + 255) / 256;
    char* base = (char*)d_ws;
    size_t off = 0;
    auto alloc = [&](size_t bytes) -> char* {
        char* p = base + off;
        off = (off + bytes + 255) & ~(size_t)255;
        return p;
    };
    int* flag = (int*)alloc(4);
    int* deg = (int*)alloc((size_t)N * 4);
    int* row_ptr = (int*)alloc((size_t)(N + 1) * 4);
    int* pos = (int*)alloc((size_t)N * 4);
    int* bsum = (int*)alloc((size_t)NB * 4);
    int* boff = (int*)alloc((size_t)NB * 4);
    int* csr = (int*)alloc((size_t)EPN * 4);
    float* bnsc1 = (float*)alloc(512); float* bnsh1 = (float*)alloc(512);
    float* bnsc2 = (float*)alloc(512); float* bnsh2 = (float*)alloc(512);
    float* AS1f = (float*)alloc(512); float* AD1f = (float*)alloc(512);
    float* AS2f = (float*)alloc(512); float* AD2f = (float*)alloc(512);
    float* AS3f = (float*)alloc(256); float* AD3f = (float*)alloc(256);
    float* B3f = (float*)alloc(256);
    unsigned short* Wl1 = (unsigned short*)alloc(32768);
    unsigned short* Wl2 = (unsigned short*)alloc(32768);
    unsigned short* WlR = (unsigned short*)alloc(32768);
    unsigned short* Wl3 = (unsigned short*)alloc(12288);
    unsigned short* xb = (unsigned short*)alloc((size_t)N * 128 * 2);
    unsigned short* xwb = (unsigned short*)alloc((size_t)N * 128 * 2);  // blocked; also xw3 rowmajor
    unsigned short* h1b = (unsigned short*)alloc((size_t)N * 128 * 2);  // blocked
    unsigned short* resb = (unsigned short*)alloc((size_t)N * 128 * 2); // blocked; later h2b
    float* es = (float*)alloc((size_t)N * 4 * 4);   // [H][N]
    float* ed = (float*)alloc((size_t)N * 4 * 4);   // [H][N]

    const int* ei = (const int*)d_in[1];

    hipMemsetAsync(deg, 0, (size_t)N * 4, stream);
    detect_kernel<<<1, THREADS, 0, stream>>>((const unsigned short*)d_in[0], 4096, flag);

    InPtrs ip;
    for (int t = 0; t < 23; t++) ip.p[t] = d_in[t];
    prep_kernel<<<28 + CB + 1024, THREADS, 0, stream>>>(ip, flag, Wl1, Wl2, WlR, Wl3,
                                                        bnsc1, bnsh1, bnsc2, bnsh2,
                                                        AS1f, AD1f, AS2f, AD2f,
                                                        AS3f, AD3f, B3f, xb, N, ei, deg, E, CB);

    bsum_kernel<<<NB, 256, 0, stream>>>(deg, bsum, N);
    bscan_kernel<<<1, 1024, 0, stream>>>(bsum, boff, NB);
    scanw_kernel<<<NB, 256, 0, stream>>>(deg, boff, row_ptr, pos, N);
    scatter_kernel<<<(EPN + THREADS - 1) / THREADS, THREADS, 0, stream>>>(ei, pos, csr, E, N);

    int gemmGrid = (N + 63) / 64;
    int passGrid = (N + 7) / 8;
    int aggGrid = (N + 3) / 4;

    // layer 1 (W1 + Wres fused GEMM; blocked C)
    gemm_dual<<<gemmGrid, 256, 0, stream>>>((const unsigned short*)d_in[0], xb, flag,
                                            Wl1, WlR, AS1f, AD1f, xwb, resb, es, ed, N);
    for (int p = 0; p < 4; ++p)
        agg128_pass<<<passGrid, 256, 0, stream>>>(xwb, es, ed, row_ptr, csr,
                                                  bnsc1, bnsh1, resb, h1b, N, p);
    // layer 2 (A = h1b blocked: aRow=32, aKs=N*32; blocked C)
    gemm_mfma<8, 4, true, true><<<gemmGrid, 256, 0, stream>>>(
        h1b, Wl2, AS2f, AD2f, xwb, 128, 128, es, ed, N, 32L, (long)N * 32);
    unsigned short* h2b = resb;  // resb free after layer-1 agg
    for (int p = 0; p < 4; ++p)
        agg128_pass<<<passGrid, 256, 0, stream>>>(xwb, es, ed, row_ptr, csr,
                                                  bnsc2, bnsh2, h1b, h2b, N, p);
    // layer 3 (A = h2b blocked; C row-major [N][40])
    gemm_mfma<3, 1, true, false><<<gemmGrid, 256, 0, stream>>>(
        h2b, Wl3, AS3f, AD3f, xwb, 40, 40, es, ed, N, 32L, (long)N * 32);
    agg40_kernel<<<aggGrid, 256, 0, stream>>>(xwb, es, ed, row_ptr, csr, B3f,
                                              d_out, flag, N);
}

// Round 9
// 291.551 us; speedup vs baseline: 1.2320x; 1.1204x over previous
//
#include <hip/hip_runtime.h>
#include <hip/hip_bf16.h>

#define THREADS 256

typedef __attribute__((ext_vector_type(8))) short bfrag;     // 8 bf16 = 4 VGPR
typedef __attribute__((ext_vector_type(4))) float f32x4;     // MFMA accumulator

__device__ inline unsigned short f2b(float v) {
    __hip_bfloat16 b = __float2bfloat16(v);
    return *reinterpret_cast<unsigned short*>(&b);
}
__device__ inline float b2f(unsigned short u) {
    return __uint_as_float(((unsigned)u) << 16);
}
__device__ inline float rdv(const void* p, int off, bool isbf) {
    return isbf ? b2f(((const unsigned short*)p)[off]) : ((const float*)p)[off];
}

// ---------------- dtype detection (bf16 vs fp32 inputs) ----------------
__global__ void detect_kernel(const unsigned short* __restrict__ x, int n, int* flag) {
    __shared__ int cnt;
    if (threadIdx.x == 0) cnt = 0;
    __syncthreads();
    int local = 0;
    for (int i = threadIdx.x; i < n; i += THREADS) {
        unsigned ex = (x[i] >> 7) & 0xFF;
        if (ex == 0xFF || ex >= 134 || (ex > 0 && ex <= 100)) local++;
    }
    atomicAdd(&cnt, local);
    __syncthreads();
    if (threadIdx.x == 0) *flag = (cnt * 8 > n) ? 0 : 1;  // 1 = bf16
}

// ---------------- fused prep: W->frag-order, BN fold, degree count, xconv ----------------
struct InPtrs { const void* p[23]; };

__global__ void prep_kernel(InPtrs in, const int* __restrict__ flag,
                            unsigned short* __restrict__ Wl1, unsigned short* __restrict__ Wl2,
                            unsigned short* __restrict__ WlR, unsigned short* __restrict__ Wl3,
                            float* __restrict__ bnsc1, float* __restrict__ bnsh1,
                            float* __restrict__ bnsc2, float* __restrict__ bnsh2,
                            float* __restrict__ AS1f, float* __restrict__ AD1f,
                            float* __restrict__ AS2f, float* __restrict__ AD2f,
                            float* __restrict__ AS3f, float* __restrict__ AD3f,
                            float* __restrict__ B3f, unsigned short* __restrict__ xb,
                            int N, const int* __restrict__ ei, int* __restrict__ deg,
                            int E, int CB) {
    bool isbf = (*flag != 0);
    int b = blockIdx.x;
    if (b < 27) {
        // W [128,cols] raw -> bf16 fragment order
        const void* Wv; unsigned short* o; int cols, tt;
        if (b < 8)       { Wv = in.p[2];  o = Wl1; cols = 128; tt = b; }
        else if (b < 16) { Wv = in.p[6];  o = Wl2; cols = 128; tt = b - 8; }
        else if (b < 24) { Wv = in.p[14]; o = WlR; cols = 128; tt = b - 16; }
        else             { Wv = in.p[10]; o = Wl3; cols = 40;  tt = b - 24; }
        int id = tt * 256 + threadIdx.x;
        int t = id >> 8, ks = (id >> 6) & 3, l = id & 63;
        int q = l >> 4, n = l & 15;
        int c = t * 16 + n;
#pragma unroll
        for (int j = 0; j < 8; ++j) {
            int k = ks * 32 + q * 8 + j;
            float v = (c < cols) ? rdv(Wv, k * cols + c, isbf) : 0.f;
            o[id * 8 + j] = f2b(v);
        }
    } else if (b == 27) {
        int c = threadIdx.x;
        if (c < 128) {
            float s = rdv(in.p[15], c, isbf) * rsqrtf(rdv(in.p[18], c, isbf) + 1e-5f);
            bnsc1[c] = s;
            bnsh1[c] = rdv(in.p[16], c, isbf) - rdv(in.p[17], c, isbf) * s +
                       rdv(in.p[5], c, isbf) * s;
            AS1f[c] = rdv(in.p[3], c, isbf);
            AD1f[c] = rdv(in.p[4], c, isbf);
            AS2f[c] = rdv(in.p[7], c, isbf);
            AD2f[c] = rdv(in.p[8], c, isbf);
        } else {
            int d = c - 128;
            float s = rdv(in.p[19], d, isbf) * rsqrtf(rdv(in.p[22], d, isbf) + 1e-5f);
            bnsc2[d] = s;
            bnsh2[d] = rdv(in.p[20], d, isbf) - rdv(in.p[21], d, isbf) * s +
                       rdv(in.p[9], d, isbf) * s;
            if (d < 40) {
                AS3f[d] = rdv(in.p[11], d, isbf);
                AD3f[d] = rdv(in.p[12], d, isbf);
                B3f[d] = rdv(in.p[13], d, isbf);
            }
        }
    } else if (b < 28 + CB) {
        int i = (b - 28) * 256 + threadIdx.x;
        if (i < E + N) {
            int d = (i < E) ? ei[E + i] : (i - E);
            atomicAdd(&deg[d], 1);
        }
    } else {
        if (isbf) return;  // bf16 path: gemm reads d_in[0] raw
        const float* xf = (const float*)in.p[0];
        int total = N * 128;
        int stride = (gridDim.x - 28 - CB) * 256;
        for (int i = (b - 28 - CB) * 256 + threadIdx.x; i < total; i += stride)
            xb[i] = f2b(xf[i]);
    }
}

// ---------------- CSR scan stages ----------------
__global__ void bsum_kernel(const int* __restrict__ deg, int* __restrict__ bsum, int N) {
    int idx = blockIdx.x * 256 + threadIdx.x;
    int lane = threadIdx.x & 63, wv = threadIdx.x >> 6;
    int v = (idx < N) ? deg[idx] : 0;
#pragma unroll
    for (int o = 1; o < 64; o <<= 1) v += __shfl_xor(v, o, 64);
    __shared__ int ws[4];
    if (lane == 0) ws[wv] = v;
    __syncthreads();
    if (threadIdx.x == 0) bsum[blockIdx.x] = ws[0] + ws[1] + ws[2] + ws[3];
}

__global__ __launch_bounds__(1024) void bscan_kernel(const int* __restrict__ bsum,
                                                     int* __restrict__ boff, int nb) {
    __shared__ int ws[16];
    int tid = threadIdx.x, lane = tid & 63, wv = tid >> 6;
    int v = (tid < nb) ? bsum[tid] : 0;
    int sc = v;
#pragma unroll
    for (int o = 1; o < 64; o <<= 1) {
        int t = __shfl_up(sc, o, 64);
        if (lane >= o) sc += t;
    }
    if (lane == 63) ws[wv] = sc;
    __syncthreads();
    int add = 0;
#pragma unroll
    for (int k = 0; k < 16; ++k) add += (k < wv) ? ws[k] : 0;
    if (tid < nb) boff[tid] = add + sc - v;
}

__global__ void scanw_kernel(const int* __restrict__ deg, const int* __restrict__ boff,
                             int* __restrict__ row_ptr, int* __restrict__ pos, int N) {
    int idx = blockIdx.x * 256 + threadIdx.x;
    int lane = threadIdx.x & 63, wv = threadIdx.x >> 6;
    int v = (idx < N) ? deg[idx] : 0;
    int sc = v;
#pragma unroll
    for (int o = 1; o < 64; o <<= 1) {
        int t = __shfl_up(sc, o, 64);
        if (lane >= o) sc += t;
    }
    __shared__ int ws[4];
    if (lane == 63) ws[wv] = sc;
    __syncthreads();
    int add = boff[blockIdx.x];
#pragma unroll
    for (int k = 0; k < 4; ++k) add += (k < wv) ? ws[k] : 0;
    int excl = add + sc - v;
    if (idx < N) {
        pos[idx] = excl;
        row_ptr[idx + 1] = excl + v;
    }
    if (idx == 0) row_ptr[0] = 0;
}

__global__ void scatter_kernel(const int* __restrict__ ei, int* __restrict__ pos,
                               int* __restrict__ csr, int E, int N) {
    int e = blockIdx.x * THREADS + threadIdx.x;
    if (e >= E + N) return;
    int s, d;
    if (e < E) { s = ei[e]; d = ei[E + e]; }
    else { s = e - E; d = s; }
    int p = atomicAdd(&pos[d], 1);
    csr[p] = s;
}

// ---------------- MFMA GEMM: [N,128]bf16 @ [128,cols]bf16 (row-major) ----------------
template <int COLT, int HEADS, bool ES>
__global__ __launch_bounds__(256) void gemm_mfma(
    const unsigned short* __restrict__ A, const unsigned short* __restrict__ Wg,
    const float* __restrict__ as_f, const float* __restrict__ ad_f,
    unsigned short* __restrict__ out, int ldc, int cols,
    float* __restrict__ es, float* __restrict__ ed, int N) {
    __shared__ __align__(16) unsigned short Wls[COLT * 2048];
    int tid = threadIdx.x;
    {
        const float4* src = (const float4*)Wg;
        float4* dst = (float4*)Wls;
#pragma unroll
        for (int i = 0; i < COLT; ++i) dst[tid + i * 256] = src[tid + i * 256];
    }
    __syncthreads();
    int w = tid >> 6, lane = tid & 63;
    int n = lane & 15, q = lane >> 4;
    int row0 = blockIdx.x * 64 + w * 16;
    int ar = row0 + n; ar = ar < N ? ar : N - 1;   // clamp: OOB rows harmless
    f32x4 acc[COLT];
#pragma unroll
    for (int t = 0; t < COLT; ++t) acc[t] = (f32x4){0.f, 0.f, 0.f, 0.f};
    const unsigned short* arow = A + (size_t)ar * 128;
#pragma unroll
    for (int ks = 0; ks < 4; ++ks) {
        bfrag a = *reinterpret_cast<const bfrag*>(arow + ks * 32 + q * 8);
#pragma unroll
        for (int t = 0; t < COLT; ++t) {
            bfrag b = *reinterpret_cast<const bfrag*>(&Wls[((t * 4 + ks) * 64 + lane) * 8]);
            acc[t] = __builtin_amdgcn_mfma_f32_16x16x32_bf16(a, b, acc[t], 0, 0, 0);
        }
    }
    if (ES) {
        float asv[COLT], adv[COLT];
#pragma unroll
        for (int t = 0; t < COLT; ++t) {
            int c = t * 16 + n;
            asv[t] = (c < cols) ? as_f[c] : 0.f;
            adv[t] = (c < cols) ? ad_f[c] : 0.f;
        }
#pragma unroll
        for (int r = 0; r < 4; ++r) {
            float pe[HEADS], pd[HEADS];
#pragma unroll
            for (int h = 0; h < HEADS; ++h) { pe[h] = 0.f; pd[h] = 0.f; }
#pragma unroll
            for (int t = 0; t < COLT; ++t) {
                int h = (HEADS == 4) ? (t >> 1) : 0;
                pe[h] = fmaf(acc[t][r], asv[t], pe[h]);
                pd[h] = fmaf(acc[t][r], adv[t], pd[h]);
            }
#pragma unroll
            for (int h = 0; h < HEADS; ++h) {
#pragma unroll
                for (int o = 1; o < 16; o <<= 1) {
                    pe[h] += __shfl_xor(pe[h], o, 64);
                    pd[h] += __shfl_xor(pd[h], o, 64);
                }
            }
            int row = row0 + q * 4 + r;
            if (n == 0 && row < N) {
#pragma unroll
                for (int h = 0; h < HEADS; ++h) {
                    es[(size_t)row * HEADS + h] = pe[h];
                    ed[(size_t)row * HEADS + h] = pd[h];
                }
            }
        }
    }
#pragma unroll
    for (int t = 0; t < COLT; ++t) {
        int col = t * 16 + n;
        if (col < cols) {
#pragma unroll
            for (int r = 0; r < 4; ++r) {
                int row = row0 + q * 4 + r;
                if (row < N) out[(size_t)row * ldc + col] = f2b(acc[t][r]);
            }
        }
    }
}

// W1 + Wres in one pass (A read once); both outputs bf16 row-major
__global__ __launch_bounds__(256) void gemm_dual(
    const unsigned short* __restrict__ Araw, const unsigned short* __restrict__ Acvt,
    const int* __restrict__ flag,
    const unsigned short* __restrict__ Wg1, const unsigned short* __restrict__ WgR,
    const float* __restrict__ as_f, const float* __restrict__ ad_f,
    unsigned short* __restrict__ xwb, unsigned short* __restrict__ resb,
    float* __restrict__ es, float* __restrict__ ed, int N) {
    __shared__ __align__(16) unsigned short Wls[16 * 2048];
    int tid = threadIdx.x;
    {
        const float4* s1 = (const float4*)Wg1;
        const float4* s2 = (const float4*)WgR;
        float4* dst = (float4*)Wls;
#pragma unroll
        for (int i = 0; i < 8; ++i) dst[tid + i * 256] = s1[tid + i * 256];
#pragma unroll
        for (int i = 0; i < 8; ++i) dst[2048 + tid + i * 256] = s2[tid + i * 256];
    }
    const unsigned short* A = (*flag) ? Araw : Acvt;
    __syncthreads();
    int w = tid >> 6, lane = tid & 63;
    int n = lane & 15, q = lane >> 4;
    int row0 = blockIdx.x * 64 + w * 16;
    int ar = row0 + n; ar = ar < N ? ar : N - 1;
    f32x4 acc[16];
#pragma unroll
    for (int t = 0; t < 16; ++t) acc[t] = (f32x4){0.f, 0.f, 0.f, 0.f};
    const unsigned short* arow = A + (size_t)ar * 128;
#pragma unroll
    for (int ks = 0; ks < 4; ++ks) {
        bfrag a = *reinterpret_cast<const bfrag*>(arow + ks * 32 + q * 8);
#pragma unroll
        for (int t = 0; t < 8; ++t) {
            bfrag b = *reinterpret_cast<const bfrag*>(&Wls[((t * 4 + ks) * 64 + lane) * 8]);
            acc[t] = __builtin_amdgcn_mfma_f32_16x16x32_bf16(a, b, acc[t], 0, 0, 0);
        }
#pragma unroll
        for (int t = 0; t < 8; ++t) {
            bfrag b = *reinterpret_cast<const bfrag*>(&Wls[16384 + ((t * 4 + ks) * 64 + lane) * 8]);
            acc[8 + t] = __builtin_amdgcn_mfma_f32_16x16x32_bf16(a, b, acc[8 + t], 0, 0, 0);
        }
    }
    float asv[8], adv[8];
#pragma unroll
    for (int t = 0; t < 8; ++t) {
        int c = t * 16 + n;
        asv[t] = as_f[c];
        adv[t] = ad_f[c];
    }
#pragma unroll
    for (int r = 0; r < 4; ++r) {
        float pe[4] = {0.f, 0.f, 0.f, 0.f}, pd[4] = {0.f, 0.f, 0.f, 0.f};
#pragma unroll
        for (int t = 0; t < 8; ++t) {
            int h = t >> 1;
            pe[h] = fmaf(acc[t][r], asv[t], pe[h]);
            pd[h] = fmaf(acc[t][r], adv[t], pd[h]);
        }
#pragma unroll
        for (int h = 0; h < 4; ++h) {
#pragma unroll
            for (int o = 1; o < 16; o <<= 1) {
                pe[h] += __shfl_xor(pe[h], o, 64);
                pd[h] += __shfl_xor(pd[h], o, 64);
            }
        }
        int row = row0 + q * 4 + r;
        if (n == 0 && row < N) {
#pragma unroll
            for (int h = 0; h < 4; ++h) {
                es[(size_t)row * 4 + h] = pe[h];
                ed[(size_t)row * 4 + h] = pd[h];
            }
        }
    }
#pragma unroll
    for (int t = 0; t < 8; ++t) {
        int col = t * 16 + n;
#pragma unroll
        for (int r = 0; r < 4; ++r) {
            int row = row0 + q * 4 + r;
            if (row < N) {
                xwb[(size_t)row * 128 + col] = f2b(acc[t][r]);
                resb[(size_t)row * 128 + col] = f2b(acc[8 + t][r]);
            }
        }
    }
}

// ---------------- agg layers 1-2 + fused BN/bias/residual/ELU ----------------
// wave/node. SCALAR csr loads (wave-uniform jb via readfirstlane -> s_load):
// index broadcast free, row gathers SGPR-base+lane-offset, each lane computes
// all 16 edge weights itself -> ZERO cross-lane ops in the loop. Padded slots:
// clamped dup index (L1 hit) x weight 0. Branch-free chunk body.
__global__ __launch_bounds__(256) void agg128_fused(
    const unsigned short* __restrict__ xwb, const float* __restrict__ es,
    const float* __restrict__ ed, const int* __restrict__ row_ptr,
    const int* __restrict__ csr, const float* __restrict__ bnsc,
    const float* __restrict__ bnsh, const unsigned short* __restrict__ resb,
    unsigned short* __restrict__ outb, int N) {
    int w = threadIdx.x >> 6, lane = threadIdx.x & 63;
    int node = blockIdx.x * 4 + w;
    if (node >= N) return;
    int h = lane >> 4;
    int c0 = lane * 2;
    float edl = ed[node * 4 + h];
    int start = __builtin_amdgcn_readfirstlane(row_ptr[node]);
    int end = __builtin_amdgcn_readfirstlane(row_ptr[node + 1]);
    float den = 0.f, a0 = 0.f, a1 = 0.f;
    for (int jb = start; jb < end; jb += 16) {
        int su[16];
#pragma unroll
        for (int u = 0; u < 16; ++u) {
            int idx = jb + u;
            idx = idx < end - 1 ? idx : end - 1;
            su[u] = csr[idx];                       // uniform addr -> s_load
        }
        unsigned uu[16];
        float ev[16];
#pragma unroll
        for (int u = 0; u < 16; ++u) {
            uu[u] = *(const unsigned*)(xwb + (size_t)su[u] * 128 + c0);
            ev[u] = es[su[u] * 4 + h];
        }
#pragma unroll
        for (int u = 0; u < 16; ++u) {
            float e = ev[u] + edl;
            e = e > 0.f ? e : 0.2f * e;
            float wg = __expf(e);
            wg = (jb + u < end) ? wg : 0.f;         // uniform cond, branch-free
            den += wg;
            a0 = fmaf(wg, __uint_as_float(uu[u] << 16), a0);
            a1 = fmaf(wg, __uint_as_float(uu[u] & 0xffff0000u), a1);
        }
    }
    float inv = 1.f / den;
    float2 sc = *(const float2*)(bnsc + c0);
    float2 sh = *(const float2*)(bnsh + c0);
    unsigned ur = *(const unsigned*)(resb + (size_t)node * 128 + c0);
    float v0 = fmaf(a0 * inv, sc.x, sh.x) + __uint_as_float(ur << 16);
    float v1 = fmaf(a1 * inv, sc.y, sh.y) + __uint_as_float(ur & 0xffff0000u);
    v0 = v0 > 0.f ? v0 : expm1f(v0);
    v1 = v1 > 0.f ? v1 : expm1f(v1);
    unsigned pk = (unsigned)f2b(v0) | ((unsigned)f2b(v1) << 16);
    *(unsigned*)(outb + (size_t)node * 128 + c0) = pk;
}

// ---------------- layer-3 agg (H=1, 40ch): round-5 form (unconditional preloads) ------
__global__ __launch_bounds__(256) void agg40_kernel(
    const unsigned short* __restrict__ xw3b, const float* __restrict__ es3,
    const float* __restrict__ ed3, const int* __restrict__ row_ptr,
    const int* __restrict__ csr, const float* __restrict__ b3,
    void* __restrict__ out, const int* __restrict__ flag, int N) {
    int w = threadIdx.x >> 6, lane = threadIdx.x & 63;
    int node = blockIdx.x * 4 + w;
    if (node >= N) return;
    int i16 = lane & 15;
    int g = lane >= 40 ? 2 : (lane >= 20 ? 1 : 0);
    int cp = lane - g * 20;
    int c0 = cp * 2; c0 = c0 > 38 ? 38 : c0;
    float edl = ed3[node];
    int start = row_ptr[node], end = row_ptr[node + 1];
    float den = 0.f, a0 = 0.f, a1 = 0.f;
    for (int jb = start; jb < end; jb += 16) {
        int cnt = end - jb; cnt = cnt < 16 ? cnt : 16;
        int sv = csr[jb + (i16 < cnt ? i16 : 0)];
        unsigned uu[6];
#pragma unroll
        for (int t = 0; t < 6; ++t) {
            int slot = 3 * t + g; slot = slot < 15 ? slot : 15;
            int s = __shfl(sv, slot, 64);
            uu[t] = *(const unsigned*)(xw3b + (size_t)s * 40 + c0);
        }
        float wgl = 0.f;
        if (i16 < cnt) {
            float e = es3[sv] + edl;
            e = e > 0.f ? e : 0.2f * e;
            wgl = __expf(e);
        }
        float d = wgl;
        d += __shfl_xor(d, 1, 64);
        d += __shfl_xor(d, 2, 64);
        d += __shfl_xor(d, 4, 64);
        d += __shfl_xor(d, 8, 64);
        den += d;
#pragma unroll
        for (int t = 0; t < 6; ++t) {
            int slot = 3 * t + g;
            int sl = slot < 15 ? slot : 15;
            float wg = __shfl(wgl, sl, 64);
            if (slot >= cnt) wg = 0.f;
            a0 = fmaf(wg, __uint_as_float(uu[t] << 16), a0);
            a1 = fmaf(wg, __uint_as_float(uu[t] & 0xffff0000u), a1);
        }
    }
    float t0 = __shfl(a0, (lane + 20) & 63, 64);
    float t1 = __shfl(a0, (lane + 40) & 63, 64);
    float u0 = __shfl(a1, (lane + 20) & 63, 64);
    float u1 = __shfl(a1, (lane + 40) & 63, 64);
    a0 += t0 + t1;
    a1 += u0 + u1;
    if (lane < 20) {
        float inv = 1.f / den;
        float v0 = a0 * inv + b3[c0];
        float v1 = a1 * inv + b3[c0 + 1];
        size_t eoff = (size_t)node * 40 + c0;
        if (*flag) {
            unsigned pk = (unsigned)f2b(v0) | ((unsigned)f2b(v1) << 16);
            *(unsigned*)((unsigned short*)out + eoff) = pk;
        } else {
            *(float2*)((float*)out + eoff) = make_float2(v0, v1);
        }
    }
}

extern "C" void kernel_launch(void* const* d_in, const int* in_sizes, int n_in,
                              void* d_out, int out_size, void* d_ws, size_t ws_size,
                              hipStream_t stream) {
    (void)n_in; (void)out_size; (void)ws_size;
    const int N = in_sizes[0] / 128;
    const int E = in_sizes[1] / 2;
    const int EPN = E + N;
    const int NB = (N + 255) / 256;
    const int CB = (EPN + 255) / 256;
    char* base = (char*)d_ws;
    size_t off = 0;
    auto alloc = [&](size_t bytes) -> char* {
        char* p = base + off;
        off = (off + bytes + 255) & ~(size_t)255;
        return p;
    };
    int* flag = (int*)alloc(4);
    int* deg = (int*)alloc((size_t)N * 4);
    int* row_ptr = (int*)alloc((size_t)(N + 1) * 4);
    int* pos = (int*)alloc((size_t)N * 4);
    int* bsum = (int*)alloc((size_t)NB * 4);
    int* boff = (int*)alloc((size_t)NB * 4);
    int* csr = (int*)alloc((size_t)EPN * 4);
    float* bnsc1 = (float*)alloc(512); float* bnsh1 = (float*)alloc(512);
    float* bnsc2 = (float*)alloc(512); float* bnsh2 = (float*)alloc(512);
    float* AS1f = (float*)alloc(512); float* AD1f = (float*)alloc(512);
    float* AS2f = (float*)alloc(512); float* AD2f = (float*)alloc(512);
    float* AS3f = (float*)alloc(256); float* AD3f = (float*)alloc(256);
    float* B3f = (float*)alloc(256);
    unsigned short* Wl1 = (unsigned short*)alloc(32768);
    unsigned short* Wl2 = (unsigned short*)alloc(32768);
    unsigned short* WlR = (unsigned short*)alloc(32768);
    unsigned short* Wl3 = (unsigned short*)alloc(12288);
    unsigned short* xb = (unsigned short*)alloc((size_t)N * 128 * 2);
    unsigned short* xwb = (unsigned short*)alloc((size_t)N * 128 * 2);  // also xw3
    unsigned short* h1b = (unsigned short*)alloc((size_t)N * 128 * 2);
    unsigned short* resb = (unsigned short*)alloc((size_t)N * 128 * 2); // later h2b
    float* es = (float*)alloc((size_t)N * 4 * 4);   // [node*4+h]
    float* ed = (float*)alloc((size_t)N * 4 * 4);

    const int* ei = (const int*)d_in[1];

    hipMemsetAsync(deg, 0, (size_t)N * 4, stream);
    detect_kernel<<<1, THREADS, 0, stream>>>((const unsigned short*)d_in[0], 4096, flag);

    InPtrs ip;
    for (int t = 0; t < 23; t++) ip.p[t] = d_in[t];
    prep_kernel<<<28 + CB + 1024, THREADS, 0, stream>>>(ip, flag, Wl1, Wl2, WlR, Wl3,
                                                        bnsc1, bnsh1, bnsc2, bnsh2,
                                                        AS1f, AD1f, AS2f, AD2f,
                                                        AS3f, AD3f, B3f, xb, N, ei, deg, E, CB);

    bsum_kernel<<<NB, 256, 0, stream>>>(deg, bsum, N);
    bscan_kernel<<<1, 1024, 0, stream>>>(bsum, boff, NB);
    scanw_kernel<<<NB, 256, 0, stream>>>(deg, boff, row_ptr, pos, N);
    scatter_kernel<<<(EPN + THREADS - 1) / THREADS, THREADS, 0, stream>>>(ei, pos, csr, E, N);

    int gemmGrid = (N + 63) / 64;
    int aggGrid = (N + 3) / 4;

    // layer 1 (W1 + Wres fused GEMM; BN/bias/res/ELU fused into agg epilogue)
    gemm_dual<<<gemmGrid, 256, 0, stream>>>((const unsigned short*)d_in[0], xb, flag,
                                            Wl1, WlR, AS1f, AD1f, xwb, resb, es, ed, N);
    agg128_fused<<<aggGrid, 256, 0, stream>>>(xwb, es, ed, row_ptr, csr,
                                              bnsc1, bnsh1, resb, h1b, N);
    // layer 2
    gemm_mfma<8, 4, true><<<gemmGrid, 256, 0, stream>>>(
        h1b, Wl2, AS2f, AD2f, xwb, 128, 128, es, ed, N);
    unsigned short* h2b = resb;  // resb free after layer-1 agg
    agg128_fused<<<aggGrid, 256, 0, stream>>>(xwb, es, ed, row_ptr, csr,
                                              bnsc2, bnsh2, h1b, h2b, N);
    // layer 3
    gemm_mfma<3, 1, true><<<gemmGrid, 256, 0, stream>>>(
        h2b, Wl3, AS3f, AD3f, xwb, 40, 40, es, ed, N);
    agg40_kernel<<<aggGrid, 256, 0, stream>>>(xwb, es, ed, row_ptr, csr, B3f,
                                              d_out, flag, N);
}